// Round 24
// baseline (111.342 us; speedup 1.0000x reference)
//
#include <hip/hip_runtime.h>

#define HH 512
#define WW 512
#define NPIX (HH*WW)
#define KK 16
#define BB 8
#define NB 192   // lovasz error histogram buckets (%64==0)
#define NBP 200  // padded LDS hist row (bank stagger)
#define CHS 128  // pixel chunks per image in k_sums (2048 px each)
#define CHV 256  // pixel chunks per image in k_hist (1024 px each)

__device__ __forceinline__ float fast_rcp(float x){ return __builtin_amdgcn_rcpf(x); }
__device__ __forceinline__ float fast_tanh(float x){
  x = fminf(fmaxf(x, -15.f), 15.f);
  float t = __expf(2.f*x);
  return (t-1.f)*fast_rcp(t+1.f);
}
__device__ __forceinline__ float fast_sigmoid(float x){
  x = fminf(fmaxf(x, -30.f), 30.f);
  return fast_rcp(1.f+__expf(-x));
}

__device__ __forceinline__ float dpp_row_sum16(float v){
  v += __int_as_float(__builtin_amdgcn_update_dpp(0, __float_as_int(v), 0x111, 0xf, 0xf, true));
  v += __int_as_float(__builtin_amdgcn_update_dpp(0, __float_as_int(v), 0x112, 0xf, 0xf, true));
  v += __int_as_float(__builtin_amdgcn_update_dpp(0, __float_as_int(v), 0x114, 0xf, 0xf, true));
  v += __int_as_float(__builtin_amdgcn_update_dpp(0, __float_as_int(v), 0x118, 0xf, 0xf, true));
  return v;
}

// ---------------- kernel 1: mask sums + bg seed + zero-hist + FUSED reduce
// grid 1024: b = bid&7, ch = bid>>3 in [0,128); 2048 px/block, 8 px/lane.
// Last-done block (device fence + counter, mod-1023 trick) folds partial_s
// into der — saves the k_reduce dispatch + gap.
__global__ void __launch_bounds__(256) k_sums(
    const float* __restrict__ pred, const int* __restrict__ inst,
    const int* __restrict__ lab, float* __restrict__ partial_s /*[B][80][128]*/,
    float* __restrict__ partial_b /*[1024]*/,
    unsigned long long* __restrict__ hist64, unsigned int* __restrict__ done2,
    float* __restrict__ der) {
  const int bid = blockIdx.x;
  const int b  = bid & 7;
  const int ch = bid >> 3;
  const int tid = threadIdx.x;
  const int wave = tid >> 6, lane = tid & 63;
  __shared__ float lred[KK][16][5];
  __shared__ float lbg[4];
  __shared__ unsigned int sOld2;
  // zero 192 B of hist64 per block (total 128*192*8 = 196,608 B exactly)
  if (tid < 48) ((unsigned int*)hist64)[bid*48 + tid] = 0u;
  const float inv = 1.f/511.f;
  const float* ps = pred + (size_t)b*4*NPIX + 2*NPIX;
  const float* pd = ps + NPIX;
  const int*   ib = inst + (size_t)b*NPIX;
  const int*   lb = lab  + (size_t)b*NPIX;
  const int p = ch*2048 + tid*8;       // 8 px, same row (8 | 512)
  int4   iv0 = *(const int4*)(ib + p),     iv1 = *(const int4*)(ib + p + 4);
  int4   lv0 = *(const int4*)(lb + p),     lv1 = *(const int4*)(lb + p + 4);
  float4 sv0 = *(const float4*)(ps + p),   sv1 = *(const float4*)(ps + p + 4);
  float4 dv0 = *(const float4*)(pd + p),   dv1 = *(const float4*)(pd + p + 4);
  const float ym  = (float)(p >> 9) * inv;
  const float xm0 = (float)(p & (WW-1)) * inv;
  int   ida[8] = {iv0.x, iv0.y, iv0.z, iv0.w, iv1.x, iv1.y, iv1.z, iv1.w};
  int   laa[8] = {lv0.x, lv0.y, lv0.z, lv0.w, lv1.x, lv1.y, lv1.z, lv1.w};
  float sga[8] = {sv0.x, sv0.y, sv0.z, sv0.w, sv1.x, sv1.y, sv1.z, sv1.w};
  float sda[8] = {dv0.x, dv0.y, dv0.z, dv0.w, dv1.x, dv1.y, dv1.z, dv1.w};
  float xja[8], sg2[8];
  #pragma unroll
  for (int j = 0; j < 8; ++j) {
    xja[j] = xm0 + (float)j*inv;
    sg2[j] = sga[j]*sga[j];
  }

  float sbg = 0.f;
  #pragma unroll
  for (int j = 0; j < 8; ++j)
    if (laa[j] == 0) { float sd = fast_sigmoid(sda[j]); sbg += sd*sd; }
  #pragma unroll
  for (int off = 32; off; off >>= 1) sbg += __shfl_down(sbg, off);
  if (lane == 0) lbg[wave] = sbg;

  #pragma unroll
  for (int k = 0; k < KK; ++k) {
    float c = 0.f, sx = 0.f, ss = 0.f, sq = 0.f;
    #pragma unroll
    for (int j = 0; j < 8; ++j) {
      float m = (ida[j] == k+1) ? 1.f : 0.f;
      c  += m;
      sx = fmaf(m, xja[j], sx);
      ss = fmaf(m, sga[j], ss);
      sq = fmaf(m, sg2[j], sq);
    }
    float sy = c * ym;
    c  = dpp_row_sum16(c);
    sx = dpp_row_sum16(sx);
    sy = dpp_row_sum16(sy);
    ss = dpp_row_sum16(ss);
    sq = dpp_row_sum16(sq);
    if ((lane & 15) == 15) {
      int g = wave*4 + (lane >> 4);
      lred[k][g][0] = c;  lred[k][g][1] = sx; lred[k][g][2] = sy;
      lred[k][g][3] = ss; lred[k][g][4] = sq;
    }
  }
  __syncthreads();
  if (tid < KK) {
    #pragma unroll
    for (int comp = 0; comp < 5; ++comp) {
      float a = 0.f;
      #pragma unroll
      for (int g = 0; g < 16; ++g) a += lred[tid][g][comp];
      partial_s[((size_t)b*80 + tid*5 + comp)*CHS + ch] = a;
    }
  }
  if (tid == 64) partial_b[bid] = lbg[0] + lbg[1] + lbg[2] + lbg[3];
  __syncthreads();
  if (tid == 0) { __threadfence(); sOld2 = atomicAdd(done2, 1u); }
  __syncthreads();
  if ((sOld2 & 1023u) != 1023u) return;   // not the last block this call
  __threadfence();                        // acquire: see all partial_s
  // ---- fused reduce: thread t<128 handles seg t ----
  if (tid < 128) {
    const int seg = tid, b2 = seg >> 4, k2 = seg & 15;
    float acc[5];
    #pragma unroll
    for (int comp = 0; comp < 5; ++comp) {
      const float* row = partial_s + ((size_t)b2*80 + k2*5 + comp)*CHS;
      float a = 0.f;
      for (int c2 = 0; c2 < CHS; ++c2) a += row[c2];
      acc[comp] = a;
    }
    float cnt = acc[0];
    float safe = fmaxf(cnt, 1.f);
    float rs = fast_rcp(safe);
    float sb = acc[3]*rs;
    float* dd = der + seg*8;
    dd[0] = acc[1]*rs; dd[1] = acc[2]*rs;
    dd[2] = __expf(10.f*sb);
    dd[3] = (cnt > 0.f) ? 1.f : 0.f;
    dd[4] = sb;
    dd[5] = cnt;
    dd[6] = acc[4] - cnt*sb*sb;      // Σ(σ−s̄)² over mask
  }
}

// ---------------- kernel 2: unified 16-instance hist + fg seed loss -------
// grid 2048: b = bid&7, ch = bid>>3 in [0,256); 1024 px/block.
// 3-FMA distance (log2e prefolded) + exp2. Flush: u64 global atomics of
// NON-ZERO buckets only into hist64[seg][NB] (no 25MB store/re-read).
__global__ void __launch_bounds__(256, 4) k_hist(
    const float* __restrict__ pred, const int* __restrict__ inst,
    const float* __restrict__ der, unsigned long long* __restrict__ hist64,
    float* __restrict__ partial_v /*[2048]*/) {
  const int bid = blockIdx.x;
  const int b  = bid & 7;
  const int ch = bid >> 3;
  const int tid = threadIdx.x;
  const int g = tid >> 4, l4 = tid & 15;   // 16 groups x 16 lanes
  __shared__ unsigned int lh[KK][NBP];
  __shared__ float sder[KK][4];
  __shared__ float lsl[4];
  if (tid < KK) {
    const float* dd = der + (b*KK + tid)*8;
    sder[tid][0] = dd[0]; sder[tid][1] = dd[1]; sder[tid][2] = dd[2];
  }
  for (int i = tid; i < KK*NBP; i += 256) ((unsigned int*)lh)[i] = 0u;
  __syncthreads();
  const float L2E = 1.4426950408889634f;
  float seaL[KK], AL[KK], BL[KK], CL[KK];
  #pragma unroll
  for (int k = 0; k < KK; ++k) {
    float cx = sder[k][0], cy = sder[k][1], se = sder[k][2];
    float seL = se * L2E;
    seaL[k] = -seL;
    AL[k] = 2.f*cx*seL;
    BL[k] = 2.f*cy*seL;
    CL[k] = -(cx*cx + cy*cy)*seL;
  }
  const float inv = 1.f/511.f;
  const float* pbx = pred + (size_t)b*4*NPIX;
  const float* pby = pbx + NPIX;
  const float* pbd = pbx + 3*NPIX;
  const int*   ib  = inst + (size_t)b*NPIX;
  const int p = ch*1024 + g*64 + l4*4;     // group-private 64-px chunk
  float4 px = *(const float4*)(pbx + p);
  float4 py = *(const float4*)(pby + p);
  int4   iv = *(const int4*)(ib + p);
  float4 dv = *(const float4*)(pbd + p);
  const float ym  = (float)(p >> 9) * inv;
  const float xm0 = (float)(p & (WW-1)) * inv;
  float pxa[4] = {px.x, px.y, px.z, px.w};
  float pya[4] = {py.x, py.y, py.z, py.w};
  int   ida[4] = {iv.x, iv.y, iv.z, iv.w};
  float sda[4] = {dv.x, dv.y, dv.z, dv.w};
  float sloss = 0.f;
  #pragma unroll
  for (int j = 0; j < 4; ++j) {
    float sex = fast_tanh(pxa[j]) + xm0 + (float)j*inv;
    float sey = fast_tanh(pya[j]) + ym;
    float s2 = fmaf(sex, sex, sey*sey);
    int id = ida[j];
    float down = 0.f;
    #pragma unroll
    for (int k = 0; k < KK; ++k) {
      float t2 = fmaf(seaL[k], s2, fmaf(AL[k], sex, fmaf(BL[k], sey, CL[k])));
      float d = __builtin_amdgcn_exp2f(t2);
      bool fg = (id == k+1);
      float dN = d * (float)NB;
      float uN = fg ? ((float)NB - dN) : dN;
      int bkt = (int)uN;
      bkt = bkt < (NB-1) ? bkt : (NB-1);
      atomicAdd(&lh[k][bkt], fg ? 0x10001u : 1u);
      down = fg ? d : down;
    }
    if (id >= 1) {
      float dsee = fast_sigmoid(sda[j]) - down;
      sloss = fmaf(dsee, dsee, sloss);
    }
  }
  __syncthreads();
  // flush NON-ZERO buckets via u64 global atomics (n in lo32, fg in hi32)
  #pragma unroll
  for (int k = 0; k < KK; ++k) {
    if (tid < NB) {
      unsigned int v = lh[k][tid];
      if (v) {
        unsigned long long add = (unsigned long long)(v & 0xffffu)
                               | ((unsigned long long)(v >> 16) << 32);
        atomicAdd(&hist64[(size_t)(b*KK + k)*NB + tid], add);
      }
    }
  }
  #pragma unroll
  for (int off = 32; off; off >>= 1) sloss += __shfl_down(sloss, off);
  if ((tid & 63) == 0) lsl[tid >> 6] = sloss;
  __syncthreads();
  if (tid == 0) partial_v[bid] = lsl[0] + lsl[1] + lsl[2] + lsl[3];
}

// ---------------- kernel 3: lovasz scan (direct u64 hist) + FUSED final ---
// grid 128. `done` never reset: (old & 127)==127 fires exactly once per call.
__global__ void __launch_bounds__(256) k_lovasz(
    const unsigned long long* __restrict__ hist64, const float* __restrict__ der,
    const float* __restrict__ partial_v, const float* __restrict__ partial_b,
    float* __restrict__ instl, unsigned int* __restrict__ done,
    float* __restrict__ out) {
  const int seg = blockIdx.x;
  const int tid = threadIdx.x;
  __shared__ unsigned int sOld;
  const float gts = der[seg*8 + 5];
  const unsigned long long* h = hist64 + (size_t)seg*NB;
  if (tid < 64) {
    const int lane = tid;
    float lsum = 0.f;
    if (gts > 0.f) {
      float carryN = 0.f, carryF = 0.f;
      #pragma unroll
      for (int it = 0; it < NB/64; ++it) {
        int bkt = NB - 1 - (it*64 + lane);
        unsigned long long v = h[bkt];
        float nb = (float)(unsigned int)(v & 0xffffffffu);
        float fb = (float)(unsigned int)(v >> 32);
        float sn = nb, sf = fb;
        #pragma unroll
        for (int off = 1; off < 64; off <<= 1) {
          float tn = __shfl_up(sn, off);
          float tf = __shfl_up(sf, off);
          if (lane >= off) { sn += tn; sf += tf; }
        }
        float Nb = carryN + sn - nb;
        float Fb = carryF + sf - fb;
        if (nb > 0.f) {
          float e  = ((float)bkt + 0.5f) * (2.0f/(float)NB);
          float j0 = 1.f - (gts - Fb) / (gts + Nb - Fb);
          float N1 = Nb + nb, F1 = Fb + fb;
          float j1 = 1.f - (gts - F1) / (gts + N1 - F1);
          lsum += e * (j1 - j0);
        }
        carryN += __shfl(sn, 63);
        carryF += __shfl(sf, 63);
      }
      #pragma unroll
      for (int off = 32; off; off >>= 1) lsum += __shfl_down(lsum, off);
    }
    if (lane == 0) {
      instl[seg] = lsum;
      __threadfence();
      sOld = atomicAdd(done, 1u);
    }
  }
  __syncthreads();
  if ((sOld & 127u) != 127u) return;
  __threadfence();
  // ---- final combine (all 256 threads) ----
  __shared__ float vtmp[256], btmp[256];
  {
    const int b8 = tid >> 5, j = tid & 31;
    float a = 0.f, c = 0.f;
    #pragma unroll
    for (int i = 0; i < 8; ++i) a += partial_v[(size_t)(j + 32*i)*8 + b8];
    #pragma unroll
    for (int i = 0; i < 4; ++i) c += partial_b[(size_t)(j + 32*i)*8 + b8];
    vtmp[tid] = a; btmp[tid] = c;
  }
  __syncthreads();
  float myv = 0.f;
  if (tid < BB) {
    int b = tid;
    float svl = 0.f, sbg = 0.f;
    #pragma unroll
    for (int j = 0; j < 32; ++j) { svl += vtmp[b*32 + j]; sbg += btmp[b*32 + j]; }
    float obj = 0.f, il = 0.f, vr = 0.f;
    for (int k = 0; k < KK; ++k) {
      int s2 = b*KK + k;
      float cnt = der[s2*8 + 5];
      if (cnt > 0.f) {
        obj += 1.f;
        il  += instl[s2];
        vr  += der[s2*8 + 6] / cnt;      // var/(N_SIGMA*safe), safe==cnt
      }
    }
    float so = fmaxf(obj, 1.f);
    myv = il/so + 10.f*vr/so + (sbg + svl)/(float)NPIX;
  }
  #pragma unroll
  for (int off = 4; off; off >>= 1) myv += __shfl_down(myv, off);
  if (tid == 0) out[0] = myv * (1.f/(float)BB);
}

extern "C" void kernel_launch(void* const* d_in, const int* in_sizes, int n_in,
                              void* d_out, int out_size, void* d_ws, size_t ws_size,
                              hipStream_t stream) {
  const float* pred = (const float*)d_in[0];
  const int*   inst = (const int*)d_in[1];
  const int*   lab  = (const int*)d_in[2];
  float* out = (float*)d_out;

  // ws layout (~0.6 MB of 256 MiB); all consumed regions written every call.
  float* der         = (float*)d_ws;                          // 128*8 f32
  float* instl       = (float*)((char*)d_ws + 4160);          // 128 f32
  unsigned int* done = (unsigned int*)((char*)d_ws + 4736);   // never reset
  unsigned int* done2= (unsigned int*)((char*)d_ws + 4740);   // never reset
  float* partial_b   = (float*)((char*)d_ws + 8192);          // 1024 f32
  float* partial_v   = (float*)((char*)d_ws + 16384);         // 2048 f32
  float* partial_s   = (float*)((char*)d_ws + 24576);         // 8*80*128 f32
  unsigned long long* hist64 = (unsigned long long*)((char*)d_ws + 360448); // 128*192*8

  k_sums  <<<BB*CHS, 256, 0, stream>>>(pred, inst, lab, partial_s, partial_b,
                                       hist64, done2, der);
  k_hist  <<<BB*CHV, 256, 0, stream>>>(pred, inst, der, hist64, partial_v);
  k_lovasz<<<BB*KK, 256, 0, stream>>>(hist64, der, partial_v, partial_b,
                                      instl, done, out);
}

// Round 25
// 75.323 us; speedup vs baseline: 1.4782x; 1.4782x over previous
//
#include <hip/hip_runtime.h>

#define HH 512
#define WW 512
#define NPIX (HH*WW)
#define KK 16
#define BB 8
#define NB 192   // lovasz error histogram buckets (%64==0)
#define NBP 200  // padded LDS hist row (bank stagger)
#define CHS 128  // pixel chunks per image in k_sums (2048 px each)
#define CHV 256  // pixel chunks per image in k_hist (1024 px each)

__device__ __forceinline__ float fast_rcp(float x){ return __builtin_amdgcn_rcpf(x); }
__device__ __forceinline__ float fast_tanh(float x){
  x = fminf(fmaxf(x, -15.f), 15.f);
  float t = __expf(2.f*x);
  return (t-1.f)*fast_rcp(t+1.f);
}
__device__ __forceinline__ float fast_sigmoid(float x){
  x = fminf(fmaxf(x, -30.f), 30.f);
  return fast_rcp(1.f+__expf(-x));
}

__device__ __forceinline__ float dpp_row_sum16(float v){
  v += __int_as_float(__builtin_amdgcn_update_dpp(0, __float_as_int(v), 0x111, 0xf, 0xf, true));
  v += __int_as_float(__builtin_amdgcn_update_dpp(0, __float_as_int(v), 0x112, 0xf, 0xf, true));
  v += __int_as_float(__builtin_amdgcn_update_dpp(0, __float_as_int(v), 0x114, 0xf, 0xf, true));
  v += __int_as_float(__builtin_amdgcn_update_dpp(0, __float_as_int(v), 0x118, 0xf, 0xf, true));
  return v;
}

// ---------------- kernel 1: mask sums (5 comps) + bg seed + zero hist64 ---
// grid 1024: b = bid&7 (XCD-affine), ch = bid>>3 in [0,128); 2048 px/block.
// R21-proven body (NO fused tail — R24 showed the tail drove regalloc to
// VGPR=32 and spilled, 54us). hist64 zeroing: 48 u32/block = 196,608 B total.
__global__ void __launch_bounds__(256) k_sums(
    const float* __restrict__ pred, const int* __restrict__ inst,
    const int* __restrict__ lab, float* __restrict__ partial_s /*[B][80][128]*/,
    float* __restrict__ partial_b /*[1024]*/,
    unsigned long long* __restrict__ hist64) {
  const int bid = blockIdx.x;
  const int b  = bid & 7;
  const int ch = bid >> 3;
  const int tid = threadIdx.x;
  const int wave = tid >> 6, lane = tid & 63;
  __shared__ float lred[KK][16][5];
  __shared__ float lbg[4];
  if (tid < 48) ((unsigned int*)hist64)[bid*48 + tid] = 0u;
  const float inv = 1.f/511.f;
  const float* ps = pred + (size_t)b*4*NPIX + 2*NPIX;
  const float* pd = ps + NPIX;
  const int*   ib = inst + (size_t)b*NPIX;
  const int*   lb = lab  + (size_t)b*NPIX;
  const int p = ch*2048 + tid*8;       // 8 px, same row (8 | 512)
  int4   iv0 = *(const int4*)(ib + p),     iv1 = *(const int4*)(ib + p + 4);
  int4   lv0 = *(const int4*)(lb + p),     lv1 = *(const int4*)(lb + p + 4);
  float4 sv0 = *(const float4*)(ps + p),   sv1 = *(const float4*)(ps + p + 4);
  float4 dv0 = *(const float4*)(pd + p),   dv1 = *(const float4*)(pd + p + 4);
  const float ym  = (float)(p >> 9) * inv;
  const float xm0 = (float)(p & (WW-1)) * inv;
  int   ida[8] = {iv0.x, iv0.y, iv0.z, iv0.w, iv1.x, iv1.y, iv1.z, iv1.w};
  int   laa[8] = {lv0.x, lv0.y, lv0.z, lv0.w, lv1.x, lv1.y, lv1.z, lv1.w};
  float sga[8] = {sv0.x, sv0.y, sv0.z, sv0.w, sv1.x, sv1.y, sv1.z, sv1.w};
  float sda[8] = {dv0.x, dv0.y, dv0.z, dv0.w, dv1.x, dv1.y, dv1.z, dv1.w};
  float xja[8], sg2[8];
  #pragma unroll
  for (int j = 0; j < 8; ++j) {
    xja[j] = xm0 + (float)j*inv;
    sg2[j] = sga[j]*sga[j];
  }

  float sbg = 0.f;
  #pragma unroll
  for (int j = 0; j < 8; ++j)
    if (laa[j] == 0) { float sd = fast_sigmoid(sda[j]); sbg += sd*sd; }
  #pragma unroll
  for (int off = 32; off; off >>= 1) sbg += __shfl_down(sbg, off);
  if (lane == 0) lbg[wave] = sbg;

  #pragma unroll
  for (int k = 0; k < KK; ++k) {
    float c = 0.f, sx = 0.f, ss = 0.f, sq = 0.f;
    #pragma unroll
    for (int j = 0; j < 8; ++j) {
      float m = (ida[j] == k+1) ? 1.f : 0.f;
      c  += m;
      sx = fmaf(m, xja[j], sx);
      ss = fmaf(m, sga[j], ss);
      sq = fmaf(m, sg2[j], sq);
    }
    float sy = c * ym;
    c  = dpp_row_sum16(c);
    sx = dpp_row_sum16(sx);
    sy = dpp_row_sum16(sy);
    ss = dpp_row_sum16(ss);
    sq = dpp_row_sum16(sq);
    if ((lane & 15) == 15) {
      int g = wave*4 + (lane >> 4);
      lred[k][g][0] = c;  lred[k][g][1] = sx; lred[k][g][2] = sy;
      lred[k][g][3] = ss; lred[k][g][4] = sq;
    }
  }
  __syncthreads();
  if (tid < KK) {
    #pragma unroll
    for (int comp = 0; comp < 5; ++comp) {
      float a = 0.f;
      #pragma unroll
      for (int g = 0; g < 16; ++g) a += lred[tid][g][comp];
      partial_s[((size_t)b*80 + tid*5 + comp)*CHS + ch] = a;
    }
  }
  if (tid == 64) partial_b[bid] = lbg[0] + lbg[1] + lbg[2] + lbg[3];
}

// ---------------- kernel 2: reduce partials -> der (grid 128, 1/seg) ------
// der[seg][8] = {cx, cy, sexp, act, sbar, cnt, var, pad}
__global__ void __launch_bounds__(128) k_reduce(
    const float* __restrict__ partial_s, float* __restrict__ der) {
  const int seg = blockIdx.x;           // b*16 + k
  const int b = seg >> 4, k = seg & 15;
  const int tid = threadIdx.x;          // 128 threads = CHS
  const int w = tid >> 6, l = tid & 63;
  __shared__ float red5[5][2];
  #pragma unroll
  for (int comp = 0; comp < 5; ++comp) {
    const float* row = partial_s + ((size_t)b*80 + k*5 + comp)*CHS;
    float a = row[tid];
    #pragma unroll
    for (int off = 32; off; off >>= 1) a += __shfl_down(a, off);
    if (l == 0) red5[comp][w] = a;
  }
  __syncthreads();
  if (tid == 0) {
    float cnt = red5[0][0]+red5[0][1];
    float sx  = red5[1][0]+red5[1][1];
    float sy  = red5[2][0]+red5[2][1];
    float ss  = red5[3][0]+red5[3][1];
    float sq  = red5[4][0]+red5[4][1];
    float safe = fmaxf(cnt, 1.f);
    float rs = fast_rcp(safe);
    float sb = ss*rs;
    float* dd = der + seg*8;
    dd[0] = sx*rs; dd[1] = sy*rs;
    dd[2] = __expf(10.f*sb);
    dd[3] = (cnt > 0.f) ? 1.f : 0.f;
    dd[4] = sb;
    dd[5] = cnt;
    dd[6] = sq - cnt*sb*sb;      // Σ(σ−s̄)² over mask
  }
}

// ---------------- kernel 3: unified 16-instance hist + fg seed loss -------
// grid 2048: b = bid&7, ch = bid>>3 in [0,256); 1024 px/block.
// 3-FMA distance (log2e prefolded) + exp2. Flush: u64 global atomics of
// NON-ZERO buckets only into hist64[seg][NB] (no 25MB store/re-read).
__global__ void __launch_bounds__(256, 4) k_hist(
    const float* __restrict__ pred, const int* __restrict__ inst,
    const float* __restrict__ der, unsigned long long* __restrict__ hist64,
    float* __restrict__ partial_v /*[2048]*/) {
  const int bid = blockIdx.x;
  const int b  = bid & 7;
  const int ch = bid >> 3;
  const int tid = threadIdx.x;
  const int g = tid >> 4, l4 = tid & 15;   // 16 groups x 16 lanes
  __shared__ unsigned int lh[KK][NBP];
  __shared__ float sder[KK][4];
  __shared__ float lsl[4];
  if (tid < KK) {
    const float* dd = der + (b*KK + tid)*8;
    sder[tid][0] = dd[0]; sder[tid][1] = dd[1]; sder[tid][2] = dd[2];
  }
  for (int i = tid; i < KK*NBP; i += 256) ((unsigned int*)lh)[i] = 0u;
  __syncthreads();
  const float L2E = 1.4426950408889634f;
  float seaL[KK], AL[KK], BL[KK], CL[KK];
  #pragma unroll
  for (int k = 0; k < KK; ++k) {
    float cx = sder[k][0], cy = sder[k][1], se = sder[k][2];
    float seL = se * L2E;
    seaL[k] = -seL;
    AL[k] = 2.f*cx*seL;
    BL[k] = 2.f*cy*seL;
    CL[k] = -(cx*cx + cy*cy)*seL;
  }
  const float inv = 1.f/511.f;
  const float* pbx = pred + (size_t)b*4*NPIX;
  const float* pby = pbx + NPIX;
  const float* pbd = pbx + 3*NPIX;
  const int*   ib  = inst + (size_t)b*NPIX;
  const int p = ch*1024 + g*64 + l4*4;     // group-private 64-px chunk
  float4 px = *(const float4*)(pbx + p);
  float4 py = *(const float4*)(pby + p);
  int4   iv = *(const int4*)(ib + p);
  float4 dv = *(const float4*)(pbd + p);
  const float ym  = (float)(p >> 9) * inv;
  const float xm0 = (float)(p & (WW-1)) * inv;
  float pxa[4] = {px.x, px.y, px.z, px.w};
  float pya[4] = {py.x, py.y, py.z, py.w};
  int   ida[4] = {iv.x, iv.y, iv.z, iv.w};
  float sda[4] = {dv.x, dv.y, dv.z, dv.w};
  float sloss = 0.f;
  #pragma unroll
  for (int j = 0; j < 4; ++j) {
    float sex = fast_tanh(pxa[j]) + xm0 + (float)j*inv;
    float sey = fast_tanh(pya[j]) + ym;
    float s2 = fmaf(sex, sex, sey*sey);
    int id = ida[j];
    float down = 0.f;
    #pragma unroll
    for (int k = 0; k < KK; ++k) {
      float t2 = fmaf(seaL[k], s2, fmaf(AL[k], sex, fmaf(BL[k], sey, CL[k])));
      float d = __builtin_amdgcn_exp2f(t2);
      bool fg = (id == k+1);
      float dN = d * (float)NB;
      float uN = fg ? ((float)NB - dN) : dN;
      int bkt = (int)uN;
      bkt = bkt < (NB-1) ? bkt : (NB-1);
      atomicAdd(&lh[k][bkt], fg ? 0x10001u : 1u);
      down = fg ? d : down;
    }
    if (id >= 1) {
      float dsee = fast_sigmoid(sda[j]) - down;
      sloss = fmaf(dsee, dsee, sloss);
    }
  }
  __syncthreads();
  // flush NON-ZERO buckets via u64 global atomics (n in lo32, fg in hi32)
  #pragma unroll
  for (int k = 0; k < KK; ++k) {
    if (tid < NB) {
      unsigned int v = lh[k][tid];
      if (v) {
        unsigned long long add = (unsigned long long)(v & 0xffffu)
                               | ((unsigned long long)(v >> 16) << 32);
        atomicAdd(&hist64[(size_t)(b*KK + k)*NB + tid], add);
      }
    }
  }
  #pragma unroll
  for (int off = 32; off; off >>= 1) sloss += __shfl_down(sloss, off);
  if ((tid & 63) == 0) lsl[tid >> 6] = sloss;
  __syncthreads();
  if (tid == 0) partial_v[bid] = lsl[0] + lsl[1] + lsl[2] + lsl[3];
}

// ---------------- kernel 4: lovasz scan (direct u64 hist) + FUSED final ---
// grid 128. `done` never reset: (old & 127)==127 fires exactly once per call.
__global__ void __launch_bounds__(256) k_lovasz(
    const unsigned long long* __restrict__ hist64, const float* __restrict__ der,
    const float* __restrict__ partial_v, const float* __restrict__ partial_b,
    float* __restrict__ instl, unsigned int* __restrict__ done,
    float* __restrict__ out) {
  const int seg = blockIdx.x;
  const int tid = threadIdx.x;
  __shared__ unsigned int sOld;
  const float gts = der[seg*8 + 5];
  const unsigned long long* h = hist64 + (size_t)seg*NB;
  if (tid < 64) {
    const int lane = tid;
    float lsum = 0.f;
    if (gts > 0.f) {
      float carryN = 0.f, carryF = 0.f;
      #pragma unroll
      for (int it = 0; it < NB/64; ++it) {
        int bkt = NB - 1 - (it*64 + lane);
        unsigned long long v = h[bkt];
        float nb = (float)(unsigned int)(v & 0xffffffffu);
        float fb = (float)(unsigned int)(v >> 32);
        float sn = nb, sf = fb;
        #pragma unroll
        for (int off = 1; off < 64; off <<= 1) {
          float tn = __shfl_up(sn, off);
          float tf = __shfl_up(sf, off);
          if (lane >= off) { sn += tn; sf += tf; }
        }
        float Nb = carryN + sn - nb;
        float Fb = carryF + sf - fb;
        if (nb > 0.f) {
          float e  = ((float)bkt + 0.5f) * (2.0f/(float)NB);
          float j0 = 1.f - (gts - Fb) / (gts + Nb - Fb);
          float N1 = Nb + nb, F1 = Fb + fb;
          float j1 = 1.f - (gts - F1) / (gts + N1 - F1);
          lsum += e * (j1 - j0);
        }
        carryN += __shfl(sn, 63);
        carryF += __shfl(sf, 63);
      }
      #pragma unroll
      for (int off = 32; off; off >>= 1) lsum += __shfl_down(lsum, off);
    }
    if (lane == 0) {
      instl[seg] = lsum;
      __threadfence();
      sOld = atomicAdd(done, 1u);
    }
  }
  __syncthreads();
  if ((sOld & 127u) != 127u) return;
  __threadfence();
  // ---- final combine (all 256 threads) ----
  __shared__ float vtmp[256], btmp[256];
  {
    const int b8 = tid >> 5, j = tid & 31;
    float a = 0.f, c = 0.f;
    #pragma unroll
    for (int i = 0; i < 8; ++i) a += partial_v[(size_t)(j + 32*i)*8 + b8];
    #pragma unroll
    for (int i = 0; i < 4; ++i) c += partial_b[(size_t)(j + 32*i)*8 + b8];
    vtmp[tid] = a; btmp[tid] = c;
  }
  __syncthreads();
  float myv = 0.f;
  if (tid < BB) {
    int b = tid;
    float svl = 0.f, sbg = 0.f;
    #pragma unroll
    for (int j = 0; j < 32; ++j) { svl += vtmp[b*32 + j]; sbg += btmp[b*32 + j]; }
    float obj = 0.f, il = 0.f, vr = 0.f;
    for (int k = 0; k < KK; ++k) {
      int s2 = b*KK + k;
      float cnt = der[s2*8 + 5];
      if (cnt > 0.f) {
        obj += 1.f;
        il  += instl[s2];
        vr  += der[s2*8 + 6] / cnt;      // var/(N_SIGMA*safe), safe==cnt
      }
    }
    float so = fmaxf(obj, 1.f);
    myv = il/so + 10.f*vr/so + (sbg + svl)/(float)NPIX;
  }
  #pragma unroll
  for (int off = 4; off; off >>= 1) myv += __shfl_down(myv, off);
  if (tid == 0) out[0] = myv * (1.f/(float)BB);
}

extern "C" void kernel_launch(void* const* d_in, const int* in_sizes, int n_in,
                              void* d_out, int out_size, void* d_ws, size_t ws_size,
                              hipStream_t stream) {
  const float* pred = (const float*)d_in[0];
  const int*   inst = (const int*)d_in[1];
  const int*   lab  = (const int*)d_in[2];
  float* out = (float*)d_out;

  // ws layout (~0.6 MB of 256 MiB); all consumed regions written every call.
  float* der         = (float*)d_ws;                          // 128*8 f32
  float* instl       = (float*)((char*)d_ws + 4160);          // 128 f32
  unsigned int* done = (unsigned int*)((char*)d_ws + 4736);   // never reset
  float* partial_b   = (float*)((char*)d_ws + 8192);          // 1024 f32
  float* partial_v   = (float*)((char*)d_ws + 16384);         // 2048 f32
  float* partial_s   = (float*)((char*)d_ws + 24576);         // 8*80*128 f32
  unsigned long long* hist64 = (unsigned long long*)((char*)d_ws + 360448); // 128*192*8

  k_sums  <<<BB*CHS, 256, 0, stream>>>(pred, inst, lab, partial_s, partial_b,
                                       hist64);
  k_reduce<<<BB*KK, 128, 0, stream>>>(partial_s, der);
  k_hist  <<<BB*CHV, 256, 0, stream>>>(pred, inst, der, hist64, partial_v);
  k_lovasz<<<BB*KK, 256, 0, stream>>>(hist64, der, partial_v, partial_b,
                                      instl, done, out);
}

// Round 26
// 55.692 us; speedup vs baseline: 1.9993x; 1.3525x over previous
//
#include <hip/hip_runtime.h>

#define HH 512
#define WW 512
#define NPIX (HH*WW)
#define KK 16
#define BB 8
#define NB 192   // lovasz error histogram buckets (%64==0)
#define NBP 200  // padded LDS hist row (bank stagger)
#define CHS 128  // pixel chunks per image in k_sums (2048 px each)
#define CHV 128  // pixel chunks per image in k_hist (2048 px each)

__device__ __forceinline__ float fast_rcp(float x){ return __builtin_amdgcn_rcpf(x); }
__device__ __forceinline__ float fast_tanh(float x){
  x = fminf(fmaxf(x, -15.f), 15.f);
  float t = __expf(2.f*x);
  return (t-1.f)*fast_rcp(t+1.f);
}
__device__ __forceinline__ float fast_sigmoid(float x){
  x = fminf(fmaxf(x, -30.f), 30.f);
  return fast_rcp(1.f+__expf(-x));
}

__device__ __forceinline__ float dpp_row_sum16(float v){
  v += __int_as_float(__builtin_amdgcn_update_dpp(0, __float_as_int(v), 0x111, 0xf, 0xf, true));
  v += __int_as_float(__builtin_amdgcn_update_dpp(0, __float_as_int(v), 0x112, 0xf, 0xf, true));
  v += __int_as_float(__builtin_amdgcn_update_dpp(0, __float_as_int(v), 0x114, 0xf, 0xf, true));
  v += __int_as_float(__builtin_amdgcn_update_dpp(0, __float_as_int(v), 0x118, 0xf, 0xf, true));
  return v;
}

// ---------------- kernel 1: mask sums (5 comps) + bg seed ------------------
// grid 1024: b = bid&7 (XCD-affine), ch = bid>>3 in [0,128); 2048 px/block.
__global__ void __launch_bounds__(256) k_sums(
    const float* __restrict__ pred, const int* __restrict__ inst,
    const int* __restrict__ lab, float* __restrict__ partial_s /*[B][80][128]*/,
    float* __restrict__ partial_b /*[1024]*/) {
  const int bid = blockIdx.x;
  const int b  = bid & 7;
  const int ch = bid >> 3;
  const int tid = threadIdx.x;
  const int wave = tid >> 6, lane = tid & 63;
  __shared__ float lred[KK][16][5];
  __shared__ float lbg[4];
  const float inv = 1.f/511.f;
  const float* ps = pred + (size_t)b*4*NPIX + 2*NPIX;
  const float* pd = ps + NPIX;
  const int*   ib = inst + (size_t)b*NPIX;
  const int*   lb = lab  + (size_t)b*NPIX;
  const int p = ch*2048 + tid*8;       // 8 px, same row (8 | 512)
  int4   iv0 = *(const int4*)(ib + p),     iv1 = *(const int4*)(ib + p + 4);
  int4   lv0 = *(const int4*)(lb + p),     lv1 = *(const int4*)(lb + p + 4);
  float4 sv0 = *(const float4*)(ps + p),   sv1 = *(const float4*)(ps + p + 4);
  float4 dv0 = *(const float4*)(pd + p),   dv1 = *(const float4*)(pd + p + 4);
  const float ym  = (float)(p >> 9) * inv;
  const float xm0 = (float)(p & (WW-1)) * inv;
  int   ida[8] = {iv0.x, iv0.y, iv0.z, iv0.w, iv1.x, iv1.y, iv1.z, iv1.w};
  int   laa[8] = {lv0.x, lv0.y, lv0.z, lv0.w, lv1.x, lv1.y, lv1.z, lv1.w};
  float sga[8] = {sv0.x, sv0.y, sv0.z, sv0.w, sv1.x, sv1.y, sv1.z, sv1.w};
  float sda[8] = {dv0.x, dv0.y, dv0.z, dv0.w, dv1.x, dv1.y, dv1.z, dv1.w};
  float xja[8], sg2[8];
  #pragma unroll
  for (int j = 0; j < 8; ++j) {
    xja[j] = xm0 + (float)j*inv;
    sg2[j] = sga[j]*sga[j];
  }

  float sbg = 0.f;
  #pragma unroll
  for (int j = 0; j < 8; ++j)
    if (laa[j] == 0) { float sd = fast_sigmoid(sda[j]); sbg += sd*sd; }
  #pragma unroll
  for (int off = 32; off; off >>= 1) sbg += __shfl_down(sbg, off);
  if (lane == 0) lbg[wave] = sbg;

  #pragma unroll
  for (int k = 0; k < KK; ++k) {
    float c = 0.f, sx = 0.f, ss = 0.f, sq = 0.f;
    #pragma unroll
    for (int j = 0; j < 8; ++j) {
      float m = (ida[j] == k+1) ? 1.f : 0.f;
      c  += m;
      sx = fmaf(m, xja[j], sx);
      ss = fmaf(m, sga[j], ss);
      sq = fmaf(m, sg2[j], sq);
    }
    float sy = c * ym;
    c  = dpp_row_sum16(c);
    sx = dpp_row_sum16(sx);
    sy = dpp_row_sum16(sy);
    ss = dpp_row_sum16(ss);
    sq = dpp_row_sum16(sq);
    if ((lane & 15) == 15) {
      int g = wave*4 + (lane >> 4);
      lred[k][g][0] = c;  lred[k][g][1] = sx; lred[k][g][2] = sy;
      lred[k][g][3] = ss; lred[k][g][4] = sq;
    }
  }
  __syncthreads();
  if (tid < KK) {
    #pragma unroll
    for (int comp = 0; comp < 5; ++comp) {
      float a = 0.f;
      #pragma unroll
      for (int g = 0; g < 16; ++g) a += lred[tid][g][comp];
      partial_s[((size_t)b*80 + tid*5 + comp)*CHS + ch] = a;
    }
  }
  if (tid == 64) partial_b[bid] = lbg[0] + lbg[1] + lbg[2] + lbg[3];
}

// ---------------- kernel 2: reduce partials -> der (grid 128, 1/seg) ------
// der[seg][8] = {cx, cy, sexp, act, sbar, cnt, var, pad}
__global__ void __launch_bounds__(128) k_reduce(
    const float* __restrict__ partial_s, float* __restrict__ der) {
  const int seg = blockIdx.x;           // b*16 + k
  const int b = seg >> 4, k = seg & 15;
  const int tid = threadIdx.x;          // 128 threads = CHS
  const int w = tid >> 6, l = tid & 63;
  __shared__ float red5[5][2];
  #pragma unroll
  for (int comp = 0; comp < 5; ++comp) {
    const float* row = partial_s + ((size_t)b*80 + k*5 + comp)*CHS;
    float a = row[tid];
    #pragma unroll
    for (int off = 32; off; off >>= 1) a += __shfl_down(a, off);
    if (l == 0) red5[comp][w] = a;
  }
  __syncthreads();
  if (tid == 0) {
    float cnt = red5[0][0]+red5[0][1];
    float sx  = red5[1][0]+red5[1][1];
    float sy  = red5[2][0]+red5[2][1];
    float ss  = red5[3][0]+red5[3][1];
    float sq  = red5[4][0]+red5[4][1];
    float safe = fmaxf(cnt, 1.f);
    float rs = fast_rcp(safe);
    float sb = ss*rs;
    float* dd = der + seg*8;
    dd[0] = sx*rs; dd[1] = sy*rs;
    dd[2] = __expf(10.f*sb);
    dd[3] = (cnt > 0.f) ? 1.f : 0.f;
    dd[4] = sb;
    dd[5] = cnt;
    dd[6] = sq - cnt*sb*sb;      // Σ(σ−s̄)² over mask
  }
}

// ---------------- kernel 3: unified 16-instance hist + fg seed loss -------
// grid 1024: b = bid&7, ch = bid>>3 in [0,128); 2048 px/block (2 batches).
// 3-FMA distance (log2e prefolded, VALIDATED R25) + exp2. Flush: plain
// coalesced stores to hist[seg][128][NB] (R25 showed global-atomic merge
// generates 250x write amplification — plain stores + collapse is faster).
__global__ void __launch_bounds__(256, 4) k_hist(
    const float* __restrict__ pred, const int* __restrict__ inst,
    const float* __restrict__ der, unsigned int* __restrict__ hist,
    float* __restrict__ partial_v /*[1024]*/) {
  const int bid = blockIdx.x;
  const int b  = bid & 7;
  const int ch = bid >> 3;
  const int tid = threadIdx.x;
  const int g = tid >> 4, l4 = tid & 15;   // 16 groups x 16 lanes
  __shared__ unsigned int lh[KK][NBP];
  __shared__ float sder[KK][4];
  __shared__ float lsl[4];
  if (tid < KK) {
    const float* dd = der + (b*KK + tid)*8;
    sder[tid][0] = dd[0]; sder[tid][1] = dd[1]; sder[tid][2] = dd[2];
  }
  for (int i = tid; i < KK*NBP; i += 256) ((unsigned int*)lh)[i] = 0u;
  __syncthreads();
  const float L2E = 1.4426950408889634f;
  float seaL[KK], AL[KK], BL[KK], CL[KK];
  #pragma unroll
  for (int k = 0; k < KK; ++k) {
    float cx = sder[k][0], cy = sder[k][1], se = sder[k][2];
    float seL = se * L2E;
    seaL[k] = -seL;
    AL[k] = 2.f*cx*seL;
    BL[k] = 2.f*cy*seL;
    CL[k] = -(cx*cx + cy*cy)*seL;
  }
  const float inv = 1.f/511.f;
  const float* pbx = pred + (size_t)b*4*NPIX;
  const float* pby = pbx + NPIX;
  const float* pbd = pbx + 3*NPIX;
  const int*   ib  = inst + (size_t)b*NPIX;
  const int base = ch*2048 + g*128;        // group-private 128-px chunk
  float sloss = 0.f;
  #pragma unroll
  for (int it = 0; it < 2; ++it) {
    const int p = base + it*64 + l4*4;
    float4 px = *(const float4*)(pbx + p);
    float4 py = *(const float4*)(pby + p);
    int4   iv = *(const int4*)(ib + p);
    float4 dv = *(const float4*)(pbd + p);
    const float ym  = (float)(p >> 9) * inv;
    const float xm0 = (float)(p & (WW-1)) * inv;
    float pxa[4] = {px.x, px.y, px.z, px.w};
    float pya[4] = {py.x, py.y, py.z, py.w};
    int   ida[4] = {iv.x, iv.y, iv.z, iv.w};
    float sda[4] = {dv.x, dv.y, dv.z, dv.w};
    #pragma unroll
    for (int j = 0; j < 4; ++j) {
      float sex = fast_tanh(pxa[j]) + xm0 + (float)j*inv;
      float sey = fast_tanh(pya[j]) + ym;
      float s2 = fmaf(sex, sex, sey*sey);
      int id = ida[j];
      float down = 0.f;
      #pragma unroll
      for (int k = 0; k < KK; ++k) {
        float t2 = fmaf(seaL[k], s2, fmaf(AL[k], sex, fmaf(BL[k], sey, CL[k])));
        float d = __builtin_amdgcn_exp2f(t2);
        bool fg = (id == k+1);
        float dN = d * (float)NB;
        float uN = fg ? ((float)NB - dN) : dN;
        int bkt = (int)uN;
        bkt = bkt < (NB-1) ? bkt : (NB-1);
        atomicAdd(&lh[k][bkt], fg ? 0x10001u : 1u);
        down = fg ? d : down;
      }
      if (id >= 1) {
        float dsee = fast_sigmoid(sda[j]) - down;
        sloss = fmaf(dsee, dsee, sloss);
      }
    }
  }
  __syncthreads();
  // flush 16 hists -> disjoint global regions (plain coalesced stores)
  #pragma unroll
  for (int k = 0; k < KK; ++k) {
    unsigned int* gh = hist + ((size_t)(b*KK + k)*CHV + ch)*NB;
    if (tid < NB) gh[tid] = lh[k][tid];
  }
  #pragma unroll
  for (int off = 32; off; off >>= 1) sloss += __shfl_down(sloss, off);
  if ((tid & 63) == 0) lsl[tid >> 6] = sloss;
  __syncthreads();
  if (tid == 0) partial_v[bid] = lsl[0] + lsl[1] + lsl[2] + lsl[3];
}

// ---------------- kernel 4: lovasz (collapse + scan) + FUSED final --------
// grid 128. `done` never reset: (old & 127)==127 fires exactly once per call.
__global__ void __launch_bounds__(256) k_lovasz(
    const unsigned int* __restrict__ hist, const float* __restrict__ der,
    const float* __restrict__ partial_v, const float* __restrict__ partial_b,
    float* __restrict__ instl, unsigned int* __restrict__ done,
    float* __restrict__ out) {
  const int seg = blockIdx.x;
  const int tid = threadIdx.x;
  __shared__ float nbL[NB], fbL[NB];
  __shared__ unsigned int sOld;
  const float gts = der[seg*8 + 5];
  const unsigned int* h = hist + (size_t)seg*CHV*NB;
  if (tid < NB) {
    unsigned int nlo = 0, nhi = 0;
    #pragma unroll 8
    for (int c = 0; c < CHV; ++c) {
      unsigned int v = h[(size_t)c*NB + tid];
      nlo += v & 0xffffu; nhi += v >> 16;
    }
    nbL[tid] = (float)nlo; fbL[tid] = (float)nhi;
  }
  __syncthreads();
  if (tid < 64) {
    const int lane = tid;
    float lsum = 0.f;
    if (gts > 0.f) {
      float carryN = 0.f, carryF = 0.f;
      #pragma unroll
      for (int it = 0; it < NB/64; ++it) {
        int bkt = NB - 1 - (it*64 + lane);
        float nb = nbL[bkt], fb = fbL[bkt];
        float sn = nb, sf = fb;
        #pragma unroll
        for (int off = 1; off < 64; off <<= 1) {
          float tn = __shfl_up(sn, off);
          float tf = __shfl_up(sf, off);
          if (lane >= off) { sn += tn; sf += tf; }
        }
        float Nb = carryN + sn - nb;
        float Fb = carryF + sf - fb;
        if (nb > 0.f) {
          float e  = ((float)bkt + 0.5f) * (2.0f/(float)NB);
          float j0 = 1.f - (gts - Fb) / (gts + Nb - Fb);
          float N1 = Nb + nb, F1 = Fb + fb;
          float j1 = 1.f - (gts - F1) / (gts + N1 - F1);
          lsum += e * (j1 - j0);
        }
        carryN += __shfl(sn, 63);
        carryF += __shfl(sf, 63);
      }
      #pragma unroll
      for (int off = 32; off; off >>= 1) lsum += __shfl_down(lsum, off);
    }
    if (lane == 0) {
      instl[seg] = lsum;
      __threadfence();
      sOld = atomicAdd(done, 1u);
    }
  }
  __syncthreads();
  if ((sOld & 127u) != 127u) return;
  __threadfence();
  // ---- final combine (all 256 threads) ----
  __shared__ float vtmp[256], btmp[256];
  {
    const int b8 = tid >> 5, j = tid & 31;
    float a = 0.f, c = 0.f;
    #pragma unroll
    for (int i = 0; i < 4; ++i) {
      a += partial_v[(size_t)(j + 32*i)*8 + b8];
      c += partial_b[(size_t)(j + 32*i)*8 + b8];
    }
    vtmp[tid] = a; btmp[tid] = c;
  }
  __syncthreads();
  float myv = 0.f;
  if (tid < BB) {
    int b = tid;
    float svl = 0.f, sbg = 0.f;
    #pragma unroll
    for (int j = 0; j < 32; ++j) { svl += vtmp[b*32 + j]; sbg += btmp[b*32 + j]; }
    float obj = 0.f, il = 0.f, vr = 0.f;
    for (int k = 0; k < KK; ++k) {
      int s2 = b*KK + k;
      float cnt = der[s2*8 + 5];
      if (cnt > 0.f) {
        obj += 1.f;
        il  += instl[s2];
        vr  += der[s2*8 + 6] / cnt;      // var/(N_SIGMA*safe), safe==cnt
      }
    }
    float so = fmaxf(obj, 1.f);
    myv = il/so + 10.f*vr/so + (sbg + svl)/(float)NPIX;
  }
  #pragma unroll
  for (int off = 4; off; off >>= 1) myv += __shfl_down(myv, off);
  if (tid == 0) out[0] = myv * (1.f/(float)BB);
}

extern "C" void kernel_launch(void* const* d_in, const int* in_sizes, int n_in,
                              void* d_out, int out_size, void* d_ws, size_t ws_size,
                              hipStream_t stream) {
  const float* pred = (const float*)d_in[0];
  const int*   inst = (const int*)d_in[1];
  const int*   lab  = (const int*)d_in[2];
  float* out = (float*)d_out;

  // ws layout (~13.3 MB of 256 MiB); all consumed regions written every call.
  float* der         = (float*)d_ws;                          // 128*8 f32
  float* instl       = (float*)((char*)d_ws + 4160);          // 128 f32
  unsigned int* done = (unsigned int*)((char*)d_ws + 4736);   // never reset
  float* partial_b   = (float*)((char*)d_ws + 8192);          // 1024 f32
  float* partial_v   = (float*)((char*)d_ws + 16384);         // 1024 f32
  float* partial_s   = (float*)((char*)d_ws + 24576);         // 8*80*128 f32
  unsigned int* hist = (unsigned int*)((char*)d_ws + 679936); // 128*128*192*4

  k_sums  <<<BB*CHS, 256, 0, stream>>>(pred, inst, lab, partial_s, partial_b);
  k_reduce<<<BB*KK, 128, 0, stream>>>(partial_s, der);
  k_hist  <<<BB*CHV, 256, 0, stream>>>(pred, inst, der, hist, partial_v);
  k_lovasz<<<BB*KK, 256, 0, stream>>>(hist, der, partial_v, partial_b,
                                      instl, done, out);
}

// Round 27
// 53.459 us; speedup vs baseline: 2.0827x; 1.0418x over previous
//
#include <hip/hip_runtime.h>

#define HH 512
#define WW 512
#define NPIX (HH*WW)
#define KK 16
#define BB 8
#define NB 128   // lovasz error histogram buckets (%64==0)
#define NBP 136  // padded LDS hist row (136%32=8 bank stagger)
#define CHS 128  // pixel chunks per image in k_sums (2048 px each)
#define CHV 128  // pixel chunks per image in k_hist (2048 px each)

__device__ __forceinline__ float fast_rcp(float x){ return __builtin_amdgcn_rcpf(x); }
__device__ __forceinline__ float fast_tanh(float x){
  x = fminf(fmaxf(x, -15.f), 15.f);
  float t = __expf(2.f*x);
  return (t-1.f)*fast_rcp(t+1.f);
}
__device__ __forceinline__ float fast_sigmoid(float x){
  x = fminf(fmaxf(x, -30.f), 30.f);
  return fast_rcp(1.f+__expf(-x));
}

__device__ __forceinline__ float dpp_row_sum16(float v){
  v += __int_as_float(__builtin_amdgcn_update_dpp(0, __float_as_int(v), 0x111, 0xf, 0xf, true));
  v += __int_as_float(__builtin_amdgcn_update_dpp(0, __float_as_int(v), 0x112, 0xf, 0xf, true));
  v += __int_as_float(__builtin_amdgcn_update_dpp(0, __float_as_int(v), 0x114, 0xf, 0xf, true));
  v += __int_as_float(__builtin_amdgcn_update_dpp(0, __float_as_int(v), 0x118, 0xf, 0xf, true));
  return v;
}

// ---------------- kernel 1: mask sums (5 comps, 4 butterflies) + bg seed ---
// grid 1024: b = bid&7 (XCD-affine), ch = bid>>3 in [0,128); 2048 px/block.
// A 16-lane group's 128 px lie in ONE row -> ym is group-uniform, so
// sy = c*ym is computed on the leader AFTER the c-butterfly (one less
// butterfly: 4x16x4 DPP instead of 5x16x4).
__global__ void __launch_bounds__(256) k_sums(
    const float* __restrict__ pred, const int* __restrict__ inst,
    const int* __restrict__ lab, float* __restrict__ partial_s /*[B][80][128]*/,
    float* __restrict__ partial_b /*[1024]*/) {
  const int bid = blockIdx.x;
  const int b  = bid & 7;
  const int ch = bid >> 3;
  const int tid = threadIdx.x;
  const int wave = tid >> 6, lane = tid & 63;
  __shared__ float lred[KK][16][5];
  __shared__ float lbg[4];
  const float inv = 1.f/511.f;
  const float* ps = pred + (size_t)b*4*NPIX + 2*NPIX;
  const float* pd = ps + NPIX;
  const int*   ib = inst + (size_t)b*NPIX;
  const int*   lb = lab  + (size_t)b*NPIX;
  const int p = ch*2048 + tid*8;       // 8 px, same row (8 | 512)
  int4   iv0 = *(const int4*)(ib + p),     iv1 = *(const int4*)(ib + p + 4);
  int4   lv0 = *(const int4*)(lb + p),     lv1 = *(const int4*)(lb + p + 4);
  float4 sv0 = *(const float4*)(ps + p),   sv1 = *(const float4*)(ps + p + 4);
  float4 dv0 = *(const float4*)(pd + p),   dv1 = *(const float4*)(pd + p + 4);
  const float ym  = (float)(p >> 9) * inv;
  const float xm0 = (float)(p & (WW-1)) * inv;
  int   ida[8] = {iv0.x, iv0.y, iv0.z, iv0.w, iv1.x, iv1.y, iv1.z, iv1.w};
  int   laa[8] = {lv0.x, lv0.y, lv0.z, lv0.w, lv1.x, lv1.y, lv1.z, lv1.w};
  float sga[8] = {sv0.x, sv0.y, sv0.z, sv0.w, sv1.x, sv1.y, sv1.z, sv1.w};
  float sda[8] = {dv0.x, dv0.y, dv0.z, dv0.w, dv1.x, dv1.y, dv1.z, dv1.w};
  float xja[8], sg2[8];
  #pragma unroll
  for (int j = 0; j < 8; ++j) {
    xja[j] = xm0 + (float)j*inv;
    sg2[j] = sga[j]*sga[j];
  }

  float sbg = 0.f;
  #pragma unroll
  for (int j = 0; j < 8; ++j)
    if (laa[j] == 0) { float sd = fast_sigmoid(sda[j]); sbg += sd*sd; }
  #pragma unroll
  for (int off = 32; off; off >>= 1) sbg += __shfl_down(sbg, off);
  if (lane == 0) lbg[wave] = sbg;

  #pragma unroll
  for (int k = 0; k < KK; ++k) {
    float c = 0.f, sx = 0.f, ss = 0.f, sq = 0.f;
    #pragma unroll
    for (int j = 0; j < 8; ++j) {
      float m = (ida[j] == k+1) ? 1.f : 0.f;
      c  += m;
      sx = fmaf(m, xja[j], sx);
      ss = fmaf(m, sga[j], ss);
      sq = fmaf(m, sg2[j], sq);
    }
    c  = dpp_row_sum16(c);
    sx = dpp_row_sum16(sx);
    ss = dpp_row_sum16(ss);
    sq = dpp_row_sum16(sq);
    if ((lane & 15) == 15) {
      int g = wave*4 + (lane >> 4);
      lred[k][g][0] = c;  lred[k][g][1] = sx; lred[k][g][2] = c*ym;
      lred[k][g][3] = ss; lred[k][g][4] = sq;
    }
  }
  __syncthreads();
  if (tid < KK) {
    #pragma unroll
    for (int comp = 0; comp < 5; ++comp) {
      float a = 0.f;
      #pragma unroll
      for (int g = 0; g < 16; ++g) a += lred[tid][g][comp];
      partial_s[((size_t)b*80 + tid*5 + comp)*CHS + ch] = a;
    }
  }
  if (tid == 64) partial_b[bid] = lbg[0] + lbg[1] + lbg[2] + lbg[3];
}

// ---------------- kernel 2: reduce partials -> der (grid 128, 1/seg) ------
// der[seg][8] = {cx, cy, sexp, act, sbar, cnt, var, pad}
__global__ void __launch_bounds__(128) k_reduce(
    const float* __restrict__ partial_s, float* __restrict__ der) {
  const int seg = blockIdx.x;           // b*16 + k
  const int b = seg >> 4, k = seg & 15;
  const int tid = threadIdx.x;          // 128 threads = CHS
  const int w = tid >> 6, l = tid & 63;
  __shared__ float red5[5][2];
  #pragma unroll
  for (int comp = 0; comp < 5; ++comp) {
    const float* row = partial_s + ((size_t)b*80 + k*5 + comp)*CHS;
    float a = row[tid];
    #pragma unroll
    for (int off = 32; off; off >>= 1) a += __shfl_down(a, off);
    if (l == 0) red5[comp][w] = a;
  }
  __syncthreads();
  if (tid == 0) {
    float cnt = red5[0][0]+red5[0][1];
    float sx  = red5[1][0]+red5[1][1];
    float sy  = red5[2][0]+red5[2][1];
    float ss  = red5[3][0]+red5[3][1];
    float sq  = red5[4][0]+red5[4][1];
    float safe = fmaxf(cnt, 1.f);
    float rs = fast_rcp(safe);
    float sb = ss*rs;
    float* dd = der + seg*8;
    dd[0] = sx*rs; dd[1] = sy*rs;
    dd[2] = __expf(10.f*sb);
    dd[3] = (cnt > 0.f) ? 1.f : 0.f;
    dd[4] = sb;
    dd[5] = cnt;
    dd[6] = sq - cnt*sb*sb;      // Σ(σ−s̄)² over mask
  }
}

// ---------------- kernel 3: unified 16-instance hist + fg seed loss -------
// grid 1024: b = bid&7, ch = bid>>3 in [0,128); 2048 px/block (2 batches).
// 3-FMA distance + exp2 (validated R25); plain coalesced store flush.
__global__ void __launch_bounds__(256, 4) k_hist(
    const float* __restrict__ pred, const int* __restrict__ inst,
    const float* __restrict__ der, unsigned int* __restrict__ hist,
    float* __restrict__ partial_v /*[1024]*/) {
  const int bid = blockIdx.x;
  const int b  = bid & 7;
  const int ch = bid >> 3;
  const int tid = threadIdx.x;
  const int g = tid >> 4, l4 = tid & 15;   // 16 groups x 16 lanes
  __shared__ unsigned int lh[KK][NBP];
  __shared__ float sder[KK][4];
  __shared__ float lsl[4];
  if (tid < KK) {
    const float* dd = der + (b*KK + tid)*8;
    sder[tid][0] = dd[0]; sder[tid][1] = dd[1]; sder[tid][2] = dd[2];
  }
  for (int i = tid; i < KK*NBP; i += 256) ((unsigned int*)lh)[i] = 0u;
  __syncthreads();
  const float L2E = 1.4426950408889634f;
  float seaL[KK], AL[KK], BL[KK], CL[KK];
  #pragma unroll
  for (int k = 0; k < KK; ++k) {
    float cx = sder[k][0], cy = sder[k][1], se = sder[k][2];
    float seL = se * L2E;
    seaL[k] = -seL;
    AL[k] = 2.f*cx*seL;
    BL[k] = 2.f*cy*seL;
    CL[k] = -(cx*cx + cy*cy)*seL;
  }
  const float inv = 1.f/511.f;
  const float* pbx = pred + (size_t)b*4*NPIX;
  const float* pby = pbx + NPIX;
  const float* pbd = pbx + 3*NPIX;
  const int*   ib  = inst + (size_t)b*NPIX;
  const int base = ch*2048 + g*128;        // group-private 128-px chunk
  float sloss = 0.f;
  #pragma unroll
  for (int it = 0; it < 2; ++it) {
    const int p = base + it*64 + l4*4;
    float4 px = *(const float4*)(pbx + p);
    float4 py = *(const float4*)(pby + p);
    int4   iv = *(const int4*)(ib + p);
    float4 dv = *(const float4*)(pbd + p);
    const float ym  = (float)(p >> 9) * inv;
    const float xm0 = (float)(p & (WW-1)) * inv;
    float pxa[4] = {px.x, px.y, px.z, px.w};
    float pya[4] = {py.x, py.y, py.z, py.w};
    int   ida[4] = {iv.x, iv.y, iv.z, iv.w};
    float sda[4] = {dv.x, dv.y, dv.z, dv.w};
    #pragma unroll
    for (int j = 0; j < 4; ++j) {
      float sex = fast_tanh(pxa[j]) + xm0 + (float)j*inv;
      float sey = fast_tanh(pya[j]) + ym;
      float s2 = fmaf(sex, sex, sey*sey);
      int id = ida[j];
      float down = 0.f;
      #pragma unroll
      for (int k = 0; k < KK; ++k) {
        float t2 = fmaf(seaL[k], s2, fmaf(AL[k], sex, fmaf(BL[k], sey, CL[k])));
        float d = __builtin_amdgcn_exp2f(t2);
        bool fg = (id == k+1);
        float dN = d * (float)NB;
        float uN = fg ? ((float)NB - dN) : dN;
        int bkt = (int)uN;
        bkt = bkt < (NB-1) ? bkt : (NB-1);
        atomicAdd(&lh[k][bkt], fg ? 0x10001u : 1u);
        down = fg ? d : down;
      }
      if (id >= 1) {
        float dsee = fast_sigmoid(sda[j]) - down;
        sloss = fmaf(dsee, dsee, sloss);
      }
    }
  }
  __syncthreads();
  // flush 16 hists -> disjoint global regions (plain coalesced stores)
  #pragma unroll
  for (int k = 0; k < KK; ++k) {
    unsigned int* gh = hist + ((size_t)(b*KK + k)*CHV + ch)*NB;
    if (tid < NB) gh[tid] = lh[k][tid];
  }
  #pragma unroll
  for (int off = 32; off; off >>= 1) sloss += __shfl_down(sloss, off);
  if ((tid & 63) == 0) lsl[tid >> 6] = sloss;
  __syncthreads();
  if (tid == 0) partial_v[bid] = lsl[0] + lsl[1] + lsl[2] + lsl[3];
}

// ---------------- kernel 4: lovasz (collapse + scan) + FUSED final --------
// grid 128. `done` never reset: (old & 127)==127 fires exactly once per call.
__global__ void __launch_bounds__(256) k_lovasz(
    const unsigned int* __restrict__ hist, const float* __restrict__ der,
    const float* __restrict__ partial_v, const float* __restrict__ partial_b,
    float* __restrict__ instl, unsigned int* __restrict__ done,
    float* __restrict__ out) {
  const int seg = blockIdx.x;
  const int tid = threadIdx.x;
  __shared__ float nbL[NB], fbL[NB];
  __shared__ unsigned int sOld;
  const float gts = der[seg*8 + 5];
  const unsigned int* h = hist + (size_t)seg*CHV*NB;
  if (tid < NB) {
    unsigned int nlo = 0, nhi = 0;
    #pragma unroll 8
    for (int c = 0; c < CHV; ++c) {
      unsigned int v = h[(size_t)c*NB + tid];
      nlo += v & 0xffffu; nhi += v >> 16;
    }
    nbL[tid] = (float)nlo; fbL[tid] = (float)nhi;
  }
  __syncthreads();
  if (tid < 64) {
    const int lane = tid;
    float lsum = 0.f;
    if (gts > 0.f) {
      float carryN = 0.f, carryF = 0.f;
      #pragma unroll
      for (int it = 0; it < NB/64; ++it) {
        int bkt = NB - 1 - (it*64 + lane);
        float nb = nbL[bkt], fb = fbL[bkt];
        float sn = nb, sf = fb;
        #pragma unroll
        for (int off = 1; off < 64; off <<= 1) {
          float tn = __shfl_up(sn, off);
          float tf = __shfl_up(sf, off);
          if (lane >= off) { sn += tn; sf += tf; }
        }
        float Nb = carryN + sn - nb;
        float Fb = carryF + sf - fb;
        if (nb > 0.f) {
          float e  = ((float)bkt + 0.5f) * (2.0f/(float)NB);
          float j0 = 1.f - (gts - Fb) / (gts + Nb - Fb);
          float N1 = Nb + nb, F1 = Fb + fb;
          float j1 = 1.f - (gts - F1) / (gts + N1 - F1);
          lsum += e * (j1 - j0);
        }
        carryN += __shfl(sn, 63);
        carryF += __shfl(sf, 63);
      }
      #pragma unroll
      for (int off = 32; off; off >>= 1) lsum += __shfl_down(lsum, off);
    }
    if (lane == 0) {
      instl[seg] = lsum;
      __threadfence();
      sOld = atomicAdd(done, 1u);
    }
  }
  __syncthreads();
  if ((sOld & 127u) != 127u) return;
  __threadfence();
  // ---- final combine (all 256 threads) ----
  __shared__ float vtmp[256], btmp[256];
  {
    const int b8 = tid >> 5, j = tid & 31;
    float a = 0.f, c = 0.f;
    #pragma unroll
    for (int i = 0; i < 4; ++i) {
      a += partial_v[(size_t)(j + 32*i)*8 + b8];
      c += partial_b[(size_t)(j + 32*i)*8 + b8];
    }
    vtmp[tid] = a; btmp[tid] = c;
  }
  __syncthreads();
  float myv = 0.f;
  if (tid < BB) {
    int b = tid;
    float svl = 0.f, sbg = 0.f;
    #pragma unroll
    for (int j = 0; j < 32; ++j) { svl += vtmp[b*32 + j]; sbg += btmp[b*32 + j]; }
    float obj = 0.f, il = 0.f, vr = 0.f;
    for (int k = 0; k < KK; ++k) {
      int s2 = b*KK + k;
      float cnt = der[s2*8 + 5];
      if (cnt > 0.f) {
        obj += 1.f;
        il  += instl[s2];
        vr  += der[s2*8 + 6] / cnt;      // var/(N_SIGMA*safe), safe==cnt
      }
    }
    float so = fmaxf(obj, 1.f);
    myv = il/so + 10.f*vr/so + (sbg + svl)/(float)NPIX;
  }
  #pragma unroll
  for (int off = 4; off; off >>= 1) myv += __shfl_down(myv, off);
  if (tid == 0) out[0] = myv * (1.f/(float)BB);
}

extern "C" void kernel_launch(void* const* d_in, const int* in_sizes, int n_in,
                              void* d_out, int out_size, void* d_ws, size_t ws_size,
                              hipStream_t stream) {
  const float* pred = (const float*)d_in[0];
  const int*   inst = (const int*)d_in[1];
  const int*   lab  = (const int*)d_in[2];
  float* out = (float*)d_out;

  // ws layout (~9.1 MB of 256 MiB); all consumed regions written every call.
  float* der         = (float*)d_ws;                          // 128*8 f32
  float* instl       = (float*)((char*)d_ws + 4160);          // 128 f32
  unsigned int* done = (unsigned int*)((char*)d_ws + 4736);   // never reset
  float* partial_b   = (float*)((char*)d_ws + 8192);          // 1024 f32
  float* partial_v   = (float*)((char*)d_ws + 16384);         // 1024 f32
  float* partial_s   = (float*)((char*)d_ws + 24576);         // 8*80*128 f32
  unsigned int* hist = (unsigned int*)((char*)d_ws + 679936); // 128*128*128*4

  k_sums  <<<BB*CHS, 256, 0, stream>>>(pred, inst, lab, partial_s, partial_b);
  k_reduce<<<BB*KK, 128, 0, stream>>>(partial_s, der);
  k_hist  <<<BB*CHV, 256, 0, stream>>>(pred, inst, der, hist, partial_v);
  k_lovasz<<<BB*KK, 256, 0, stream>>>(hist, der, partial_v, partial_b,
                                      instl, done, out);
}

// Round 28
// 51.732 us; speedup vs baseline: 2.1523x; 1.0334x over previous
//
#include <hip/hip_runtime.h>

#define HH 512
#define WW 512
#define NPIX (HH*WW)
#define KK 16
#define BB 8
#define NB 128   // lovasz error histogram buckets (= 2^7)
#define NBP 136  // padded LDS hist row (136%32=8 bank stagger)
#define CHS 128  // pixel chunks per image in k_sums (2048 px each)
#define CHV 128  // pixel chunks per image in k_hist (2048 px each)

__device__ __forceinline__ float fast_rcp(float x){ return __builtin_amdgcn_rcpf(x); }
__device__ __forceinline__ float fast_tanh(float x){
  x = fminf(fmaxf(x, -15.f), 15.f);
  float t = __expf(2.f*x);
  return (t-1.f)*fast_rcp(t+1.f);
}
__device__ __forceinline__ float fast_sigmoid(float x){
  x = fminf(fmaxf(x, -30.f), 30.f);
  return fast_rcp(1.f+__expf(-x));
}

__device__ __forceinline__ float dpp_row_sum16(float v){
  v += __int_as_float(__builtin_amdgcn_update_dpp(0, __float_as_int(v), 0x111, 0xf, 0xf, true));
  v += __int_as_float(__builtin_amdgcn_update_dpp(0, __float_as_int(v), 0x112, 0xf, 0xf, true));
  v += __int_as_float(__builtin_amdgcn_update_dpp(0, __float_as_int(v), 0x114, 0xf, 0xf, true));
  v += __int_as_float(__builtin_amdgcn_update_dpp(0, __float_as_int(v), 0x118, 0xf, 0xf, true));
  return v;
}

// ---------------- kernel 1: mask sums (5 comps, 4 butterflies) + bg seed ---
// grid 1024: b = bid&7 (XCD-affine), ch = bid>>3 in [0,128); 2048 px/block.
__global__ void __launch_bounds__(256) k_sums(
    const float* __restrict__ pred, const int* __restrict__ inst,
    const int* __restrict__ lab, float* __restrict__ partial_s /*[B][80][128]*/,
    float* __restrict__ partial_b /*[1024]*/) {
  const int bid = blockIdx.x;
  const int b  = bid & 7;
  const int ch = bid >> 3;
  const int tid = threadIdx.x;
  const int wave = tid >> 6, lane = tid & 63;
  __shared__ float lred[KK][16][5];
  __shared__ float lbg[4];
  const float inv = 1.f/511.f;
  const float* ps = pred + (size_t)b*4*NPIX + 2*NPIX;
  const float* pd = ps + NPIX;
  const int*   ib = inst + (size_t)b*NPIX;
  const int*   lb = lab  + (size_t)b*NPIX;
  const int p = ch*2048 + tid*8;       // 8 px, same row (8 | 512)
  int4   iv0 = *(const int4*)(ib + p),     iv1 = *(const int4*)(ib + p + 4);
  int4   lv0 = *(const int4*)(lb + p),     lv1 = *(const int4*)(lb + p + 4);
  float4 sv0 = *(const float4*)(ps + p),   sv1 = *(const float4*)(ps + p + 4);
  float4 dv0 = *(const float4*)(pd + p),   dv1 = *(const float4*)(pd + p + 4);
  const float ym  = (float)(p >> 9) * inv;
  const float xm0 = (float)(p & (WW-1)) * inv;
  int   ida[8] = {iv0.x, iv0.y, iv0.z, iv0.w, iv1.x, iv1.y, iv1.z, iv1.w};
  int   laa[8] = {lv0.x, lv0.y, lv0.z, lv0.w, lv1.x, lv1.y, lv1.z, lv1.w};
  float sga[8] = {sv0.x, sv0.y, sv0.z, sv0.w, sv1.x, sv1.y, sv1.z, sv1.w};
  float sda[8] = {dv0.x, dv0.y, dv0.z, dv0.w, dv1.x, dv1.y, dv1.z, dv1.w};
  float xja[8], sg2[8];
  #pragma unroll
  for (int j = 0; j < 8; ++j) {
    xja[j] = xm0 + (float)j*inv;
    sg2[j] = sga[j]*sga[j];
  }

  float sbg = 0.f;
  #pragma unroll
  for (int j = 0; j < 8; ++j)
    if (laa[j] == 0) { float sd = fast_sigmoid(sda[j]); sbg += sd*sd; }
  #pragma unroll
  for (int off = 32; off; off >>= 1) sbg += __shfl_down(sbg, off);
  if (lane == 0) lbg[wave] = sbg;

  #pragma unroll
  for (int k = 0; k < KK; ++k) {
    float c = 0.f, sx = 0.f, ss = 0.f, sq = 0.f;
    #pragma unroll
    for (int j = 0; j < 8; ++j) {
      float m = (ida[j] == k+1) ? 1.f : 0.f;
      c  += m;
      sx = fmaf(m, xja[j], sx);
      ss = fmaf(m, sga[j], ss);
      sq = fmaf(m, sg2[j], sq);
    }
    c  = dpp_row_sum16(c);
    sx = dpp_row_sum16(sx);
    ss = dpp_row_sum16(ss);
    sq = dpp_row_sum16(sq);
    if ((lane & 15) == 15) {
      int g = wave*4 + (lane >> 4);
      lred[k][g][0] = c;  lred[k][g][1] = sx; lred[k][g][2] = c*ym;
      lred[k][g][3] = ss; lred[k][g][4] = sq;
    }
  }
  __syncthreads();
  if (tid < KK) {
    #pragma unroll
    for (int comp = 0; comp < 5; ++comp) {
      float a = 0.f;
      #pragma unroll
      for (int g = 0; g < 16; ++g) a += lred[tid][g][comp];
      partial_s[((size_t)b*80 + tid*5 + comp)*CHS + ch] = a;
    }
  }
  if (tid == 64) partial_b[bid] = lbg[0] + lbg[1] + lbg[2] + lbg[3];
}

// ---------------- kernel 2: unified 16-instance hist + fg seed loss -------
// grid 1024: b = bid&7, ch = bid>>3 in [0,128); 2048 px/block (2 batches).
// Computes its own sder from partial_s in-block (threads 0-63 fold rows
// while threads 64-255 zero the LDS hist) — k_reduce dispatch eliminated.
// dN = exp2(t2 + 7) folds the xNB multiply into the constant; `down` select
// removed from the inner loop (own-instance d recomputed per fg pixel from
// LDS sder with a dynamic LDS index).
__global__ void __launch_bounds__(256, 4) k_hist(
    const float* __restrict__ pred, const int* __restrict__ inst,
    const float* __restrict__ partial_s, unsigned int* __restrict__ hist,
    float* __restrict__ partial_v /*[1024]*/) {
  const int bid = blockIdx.x;
  const int b  = bid & 7;
  const int ch = bid >> 3;
  const int tid = threadIdx.x;
  const int g = tid >> 4, l4 = tid & 15;   // 16 groups x 16 lanes
  __shared__ unsigned int lh[KK][NBP];
  __shared__ float sred[KK][4];
  __shared__ float sder[KK][3];   // cx, cy, sexp
  __shared__ float lsl[4];
  if (tid < 64) {                 // fold cnt,sx,sy,ss rows (L2-resident)
    int k = tid >> 2, comp = tid & 3;
    const float* row = partial_s + ((size_t)b*80 + k*5 + comp)*CHS;
    float a = 0.f;
    #pragma unroll 8
    for (int c = 0; c < CHS; ++c) a += row[c];
    sred[k][comp] = a;
  } else {                        // zero LDS hist concurrently
    for (int i = tid - 64; i < KK*NBP; i += 192) ((unsigned int*)lh)[i] = 0u;
  }
  __syncthreads();
  if (tid < KK) {
    float rs = fast_rcp(fmaxf(sred[tid][0], 1.f));
    sder[tid][0] = sred[tid][1]*rs;
    sder[tid][1] = sred[tid][2]*rs;
    sder[tid][2] = __expf(10.f*sred[tid][3]*rs);
  }
  __syncthreads();
  const float L2E = 1.4426950408889634f;
  float seaL[KK], AL[KK], BL[KK], CL7[KK];
  #pragma unroll
  for (int k = 0; k < KK; ++k) {
    float cx = sder[k][0], cy = sder[k][1], se = sder[k][2];
    float seL = se * L2E;
    seaL[k] = -seL;
    AL[k] = 2.f*cx*seL;
    BL[k] = 2.f*cy*seL;
    CL7[k] = 7.f - (cx*cx + cy*cy)*seL;   // +7: dN = d*128 = exp2(t2+7)
  }
  const float inv = 1.f/511.f;
  const float* pbx = pred + (size_t)b*4*NPIX;
  const float* pby = pbx + NPIX;
  const float* pbd = pbx + 3*NPIX;
  const int*   ib  = inst + (size_t)b*NPIX;
  const int base = ch*2048 + g*128;        // group-private 128-px chunk
  float sloss = 0.f;
  #pragma unroll
  for (int it = 0; it < 2; ++it) {
    const int p = base + it*64 + l4*4;
    float4 px = *(const float4*)(pbx + p);
    float4 py = *(const float4*)(pby + p);
    int4   iv = *(const int4*)(ib + p);
    float4 dv = *(const float4*)(pbd + p);
    const float ym  = (float)(p >> 9) * inv;
    const float xm0 = (float)(p & (WW-1)) * inv;
    float pxa[4] = {px.x, px.y, px.z, px.w};
    float pya[4] = {py.x, py.y, py.z, py.w};
    int   ida[4] = {iv.x, iv.y, iv.z, iv.w};
    float sda[4] = {dv.x, dv.y, dv.z, dv.w};
    #pragma unroll
    for (int j = 0; j < 4; ++j) {
      float sex = fast_tanh(pxa[j]) + xm0 + (float)j*inv;
      float sey = fast_tanh(pya[j]) + ym;
      float s2 = fmaf(sex, sex, sey*sey);
      int id = ida[j];
      #pragma unroll
      for (int k = 0; k < KK; ++k) {
        float t2 = fmaf(seaL[k], s2, fmaf(AL[k], sex, fmaf(BL[k], sey, CL7[k])));
        float dN = __builtin_amdgcn_exp2f(t2);
        bool fg = (id == k+1);
        float uN = fg ? ((float)NB - dN) : dN;
        int bkt = (int)uN;
        bkt = bkt < (NB-1) ? bkt : (NB-1);
        atomicAdd(&lh[k][bkt], fg ? 0x10001u : 1u);
      }
      if (id >= 1) {              // own-instance d recomputed (LDS sder)
        float cx = sder[id-1][0], cy = sder[id-1][1], se = sder[id-1][2];
        float dx = sex - cx, dy = sey - cy;
        float dwn = __builtin_amdgcn_exp2f(-se*L2E*fmaf(dx,dx,dy*dy));
        float dsee = fast_sigmoid(sda[j]) - dwn;
        sloss = fmaf(dsee, dsee, sloss);
      }
    }
  }
  __syncthreads();
  // flush 16 hists -> disjoint global regions (plain coalesced stores)
  #pragma unroll
  for (int k = 0; k < KK; ++k) {
    unsigned int* gh = hist + ((size_t)(b*KK + k)*CHV + ch)*NB;
    if (tid < NB) gh[tid] = lh[k][tid];
  }
  #pragma unroll
  for (int off = 32; off; off >>= 1) sloss += __shfl_down(sloss, off);
  if ((tid & 63) == 0) lsl[tid >> 6] = sloss;
  __syncthreads();
  if (tid == 0) partial_v[bid] = lsl[0] + lsl[1] + lsl[2] + lsl[3];
}

// ---------------- kernel 3: lovasz (collapse + scan) + FUSED final --------
// grid 128. Computes its own cnt/var (wave-2 lanes, overlapped with the
// collapse) and publishes {cnt,var} to der2 before the done bump; the
// release/acquire pair orders them for the last block's combine.
// `done` never reset: (old & 127)==127 fires exactly once per call.
__global__ void __launch_bounds__(256) k_lovasz(
    const unsigned int* __restrict__ hist, const float* __restrict__ partial_s,
    const float* __restrict__ partial_v, const float* __restrict__ partial_b,
    float* __restrict__ instl, float* __restrict__ der2,
    unsigned int* __restrict__ done, float* __restrict__ out) {
  const int seg = blockIdx.x;
  const int b = seg >> 4, k = seg & 15;
  const int tid = threadIdx.x;
  __shared__ float nbL[NB], fbL[NB];
  __shared__ float s3[3];         // cnt, ss, sq
  __shared__ unsigned int sOld;
  const unsigned int* h = hist + (size_t)seg*CHV*NB;
  if (tid < NB) {
    unsigned int nlo = 0, nhi = 0;
    #pragma unroll 8
    for (int c = 0; c < CHV; ++c) {
      unsigned int v = h[(size_t)c*NB + tid];
      nlo += v & 0xffffu; nhi += v >> 16;
    }
    nbL[tid] = (float)nlo; fbL[tid] = (float)nhi;
  } else if (tid >= 128 && tid < 131) {  // fold cnt/ss/sq rows concurrently
    int comp = (tid == 128) ? 0 : (tid == 129) ? 3 : 4;
    const float* row = partial_s + ((size_t)b*80 + k*5 + comp)*CHS;
    float a = 0.f;
    #pragma unroll 8
    for (int c = 0; c < CHS; ++c) a += row[c];
    s3[tid - 128] = a;
  }
  __syncthreads();
  const float gts = s3[0];
  if (tid < 64) {
    const int lane = tid;
    float lsum = 0.f;
    if (gts > 0.f) {
      float carryN = 0.f, carryF = 0.f;
      #pragma unroll
      for (int it = 0; it < NB/64; ++it) {
        int bkt = NB - 1 - (it*64 + lane);
        float nb = nbL[bkt], fb = fbL[bkt];
        float sn = nb, sf = fb;
        #pragma unroll
        for (int off = 1; off < 64; off <<= 1) {
          float tn = __shfl_up(sn, off);
          float tf = __shfl_up(sf, off);
          if (lane >= off) { sn += tn; sf += tf; }
        }
        float Nb = carryN + sn - nb;
        float Fb = carryF + sf - fb;
        if (nb > 0.f) {
          float e  = ((float)bkt + 0.5f) * (2.0f/(float)NB);
          float j0 = 1.f - (gts - Fb) / (gts + Nb - Fb);
          float N1 = Nb + nb, F1 = Fb + fb;
          float j1 = 1.f - (gts - F1) / (gts + N1 - F1);
          lsum += e * (j1 - j0);
        }
        carryN += __shfl(sn, 63);
        carryF += __shfl(sf, 63);
      }
      #pragma unroll
      for (int off = 32; off; off >>= 1) lsum += __shfl_down(lsum, off);
    }
    if (lane == 0) {
      float cnt = gts;
      float sb = s3[1] * fast_rcp(fmaxf(cnt, 1.f));
      instl[seg] = lsum;
      der2[seg*2 + 0] = cnt;
      der2[seg*2 + 1] = s3[2] - cnt*sb*sb;   // Σ(σ−s̄)² over mask
      __threadfence();
      sOld = atomicAdd(done, 1u);
    }
  }
  __syncthreads();
  if ((sOld & 127u) != 127u) return;
  __threadfence();
  // ---- final combine (all 256 threads) ----
  __shared__ float vtmp[256], btmp[256];
  {
    const int b8 = tid >> 5, j = tid & 31;
    float a = 0.f, c = 0.f;
    #pragma unroll
    for (int i = 0; i < 4; ++i) {
      a += partial_v[(size_t)(j + 32*i)*8 + b8];
      c += partial_b[(size_t)(j + 32*i)*8 + b8];
    }
    vtmp[tid] = a; btmp[tid] = c;
  }
  __syncthreads();
  float myv = 0.f;
  if (tid < BB) {
    int bb = tid;
    float svl = 0.f, sbg = 0.f;
    #pragma unroll
    for (int j = 0; j < 32; ++j) { svl += vtmp[bb*32 + j]; sbg += btmp[bb*32 + j]; }
    float obj = 0.f, il = 0.f, vr = 0.f;
    for (int kk = 0; kk < KK; ++kk) {
      int s2 = bb*KK + kk;
      float cnt = der2[s2*2 + 0];
      if (cnt > 0.f) {
        obj += 1.f;
        il  += instl[s2];
        vr  += der2[s2*2 + 1] / cnt;     // var/(N_SIGMA*safe), safe==cnt
      }
    }
    float so = fmaxf(obj, 1.f);
    myv = il/so + 10.f*vr/so + (sbg + svl)/(float)NPIX;
  }
  #pragma unroll
  for (int off = 4; off; off >>= 1) myv += __shfl_down(myv, off);
  if (tid == 0) out[0] = myv * (1.f/(float)BB);
}

extern "C" void kernel_launch(void* const* d_in, const int* in_sizes, int n_in,
                              void* d_out, int out_size, void* d_ws, size_t ws_size,
                              hipStream_t stream) {
  const float* pred = (const float*)d_in[0];
  const int*   inst = (const int*)d_in[1];
  const int*   lab  = (const int*)d_in[2];
  float* out = (float*)d_out;

  // ws layout (~9.1 MB of 256 MiB); all consumed regions written every call.
  float* instl       = (float*)d_ws;                          // 128 f32
  float* der2        = (float*)((char*)d_ws + 1024);          // 256 f32
  unsigned int* done = (unsigned int*)((char*)d_ws + 2048);   // never reset
  float* partial_b   = (float*)((char*)d_ws + 8192);          // 1024 f32
  float* partial_v   = (float*)((char*)d_ws + 16384);         // 1024 f32
  float* partial_s   = (float*)((char*)d_ws + 24576);         // 8*80*128 f32
  unsigned int* hist = (unsigned int*)((char*)d_ws + 679936); // 128*128*128*4

  k_sums  <<<BB*CHS, 256, 0, stream>>>(pred, inst, lab, partial_s, partial_b);
  k_hist  <<<BB*CHV, 256, 0, stream>>>(pred, inst, partial_s, hist, partial_v);
  k_lovasz<<<BB*KK, 256, 0, stream>>>(hist, partial_s, partial_v, partial_b,
                                      instl, der2, done, out);
}

// Round 29
// 50.801 us; speedup vs baseline: 2.1917x; 1.0183x over previous
//
#include <hip/hip_runtime.h>

#define HH 512
#define WW 512
#define NPIX (HH*WW)
#define KK 16
#define BB 8
#define NB 128   // lovasz error histogram buckets (= 2^7)
#define NBP 136  // padded LDS hist row (136%32=8 bank stagger)
#define CHS 128  // pixel chunks per image in k_sums (2048 px each)
#define CHV 128  // pixel chunks per image in k_hist (2048 px each)

__device__ __forceinline__ float fast_rcp(float x){ return __builtin_amdgcn_rcpf(x); }
__device__ __forceinline__ float fast_tanh(float x){
  x = fminf(fmaxf(x, -15.f), 15.f);
  float t = __expf(2.f*x);
  return (t-1.f)*fast_rcp(t+1.f);
}
__device__ __forceinline__ float fast_sigmoid(float x){
  x = fminf(fmaxf(x, -30.f), 30.f);
  return fast_rcp(1.f+__expf(-x));
}

__device__ __forceinline__ float dpp_row_sum16(float v){
  v += __int_as_float(__builtin_amdgcn_update_dpp(0, __float_as_int(v), 0x111, 0xf, 0xf, true));
  v += __int_as_float(__builtin_amdgcn_update_dpp(0, __float_as_int(v), 0x112, 0xf, 0xf, true));
  v += __int_as_float(__builtin_amdgcn_update_dpp(0, __float_as_int(v), 0x114, 0xf, 0xf, true));
  v += __int_as_float(__builtin_amdgcn_update_dpp(0, __float_as_int(v), 0x118, 0xf, 0xf, true));
  return v;
}

// ---------------- kernel 1: mask sums (5 comps, 4 butterflies) + bg seed ---
// grid 1024: b = bid&7 (XCD-affine), ch = bid>>3 in [0,128); 2048 px/block.
__global__ void __launch_bounds__(256) k_sums(
    const float* __restrict__ pred, const int* __restrict__ inst,
    const int* __restrict__ lab, float* __restrict__ partial_s /*[B][80][128]*/,
    float* __restrict__ partial_b /*[1024]*/) {
  const int bid = blockIdx.x;
  const int b  = bid & 7;
  const int ch = bid >> 3;
  const int tid = threadIdx.x;
  const int wave = tid >> 6, lane = tid & 63;
  __shared__ float lred[KK][16][5];
  __shared__ float lbg[4];
  const float inv = 1.f/511.f;
  const float* ps = pred + (size_t)b*4*NPIX + 2*NPIX;
  const float* pd = ps + NPIX;
  const int*   ib = inst + (size_t)b*NPIX;
  const int*   lb = lab  + (size_t)b*NPIX;
  const int p = ch*2048 + tid*8;       // 8 px, same row (8 | 512)
  int4   iv0 = *(const int4*)(ib + p),     iv1 = *(const int4*)(ib + p + 4);
  int4   lv0 = *(const int4*)(lb + p),     lv1 = *(const int4*)(lb + p + 4);
  float4 sv0 = *(const float4*)(ps + p),   sv1 = *(const float4*)(ps + p + 4);
  float4 dv0 = *(const float4*)(pd + p),   dv1 = *(const float4*)(pd + p + 4);
  const float ym  = (float)(p >> 9) * inv;
  const float xm0 = (float)(p & (WW-1)) * inv;
  int   ida[8] = {iv0.x, iv0.y, iv0.z, iv0.w, iv1.x, iv1.y, iv1.z, iv1.w};
  int   laa[8] = {lv0.x, lv0.y, lv0.z, lv0.w, lv1.x, lv1.y, lv1.z, lv1.w};
  float sga[8] = {sv0.x, sv0.y, sv0.z, sv0.w, sv1.x, sv1.y, sv1.z, sv1.w};
  float sda[8] = {dv0.x, dv0.y, dv0.z, dv0.w, dv1.x, dv1.y, dv1.z, dv1.w};
  float xja[8], sg2[8];
  #pragma unroll
  for (int j = 0; j < 8; ++j) {
    xja[j] = xm0 + (float)j*inv;
    sg2[j] = sga[j]*sga[j];
  }

  float sbg = 0.f;
  #pragma unroll
  for (int j = 0; j < 8; ++j)
    if (laa[j] == 0) { float sd = fast_sigmoid(sda[j]); sbg += sd*sd; }
  #pragma unroll
  for (int off = 32; off; off >>= 1) sbg += __shfl_down(sbg, off);
  if (lane == 0) lbg[wave] = sbg;

  #pragma unroll
  for (int k = 0; k < KK; ++k) {
    float c = 0.f, sx = 0.f, ss = 0.f, sq = 0.f;
    #pragma unroll
    for (int j = 0; j < 8; ++j) {
      float m = (ida[j] == k+1) ? 1.f : 0.f;
      c  += m;
      sx = fmaf(m, xja[j], sx);
      ss = fmaf(m, sga[j], ss);
      sq = fmaf(m, sg2[j], sq);
    }
    c  = dpp_row_sum16(c);
    sx = dpp_row_sum16(sx);
    ss = dpp_row_sum16(ss);
    sq = dpp_row_sum16(sq);
    if ((lane & 15) == 15) {
      int g = wave*4 + (lane >> 4);
      lred[k][g][0] = c;  lred[k][g][1] = sx; lred[k][g][2] = c*ym;
      lred[k][g][3] = ss; lred[k][g][4] = sq;
    }
  }
  __syncthreads();
  if (tid < KK) {
    #pragma unroll
    for (int comp = 0; comp < 5; ++comp) {
      float a = 0.f;
      #pragma unroll
      for (int g = 0; g < 16; ++g) a += lred[tid][g][comp];
      partial_s[((size_t)b*80 + tid*5 + comp)*CHS + ch] = a;
    }
  }
  if (tid == 64) partial_b[bid] = lbg[0] + lbg[1] + lbg[2] + lbg[3];
}

// ---------------- kernel 2: unified 16-instance hist + fg seed loss -------
// grid 1024: b = bid&7, ch = bid>>3 in [0,128); 2048 px/block (2 batches).
// Branch-free inner loop: EVERY pixel histogrammed as background
// (no fg compare/selects); rare fg pixels (6%) fixed up post-loop with
// -1/+0x10001 atomics. Bucket identity loop<->fixup guaranteed by loading
// both coefficient copies from the same LDS table (bit-identical math).
// Same-lane ds ops to one address are ordered -> the -1 can't underflow.
__global__ void __launch_bounds__(256, 4) k_hist(
    const float* __restrict__ pred, const int* __restrict__ inst,
    const float* __restrict__ partial_s, unsigned int* __restrict__ hist,
    float* __restrict__ partial_v /*[1024]*/) {
  const int bid = blockIdx.x;
  const int b  = bid & 7;
  const int ch = bid >> 3;
  const int tid = threadIdx.x;
  const int g = tid >> 4, l4 = tid & 15;   // 16 groups x 16 lanes
  __shared__ unsigned int lh[KK][NBP];
  __shared__ float sred[KK][4];
  __shared__ float co[KK][4];     // seaL, AL, BL, CL7 (shared + reg copies)
  __shared__ float lsl[4];
  if (tid < 64) {                 // fold cnt,sx,sy,ss rows (L2-resident)
    int k = tid >> 2, comp = tid & 3;
    const float* row = partial_s + ((size_t)b*80 + k*5 + comp)*CHS;
    float a = 0.f;
    #pragma unroll 8
    for (int c = 0; c < CHS; ++c) a += row[c];
    sred[k][comp] = a;
  } else {                        // zero LDS hist concurrently
    for (int i = tid - 64; i < KK*NBP; i += 192) ((unsigned int*)lh)[i] = 0u;
  }
  __syncthreads();
  const float L2E = 1.4426950408889634f;
  if (tid < KK) {
    float rs = fast_rcp(fmaxf(sred[tid][0], 1.f));
    float cx = sred[tid][1]*rs;
    float cy = sred[tid][2]*rs;
    float se = __expf(10.f*sred[tid][3]*rs);
    float seL = se * L2E;
    co[tid][0] = -seL;
    co[tid][1] = 2.f*cx*seL;
    co[tid][2] = 2.f*cy*seL;
    co[tid][3] = 7.f - (cx*cx + cy*cy)*seL;   // +7: dN = d*128 = exp2(t2+7)
  }
  __syncthreads();
  float seaL[KK], AL[KK], BL[KK], CL7[KK];
  #pragma unroll
  for (int k = 0; k < KK; ++k) {   // register copies FROM the LDS table
    seaL[k] = co[k][0]; AL[k] = co[k][1];
    BL[k]  = co[k][2]; CL7[k] = co[k][3];
  }
  const float inv = 1.f/511.f;
  const float* pbx = pred + (size_t)b*4*NPIX;
  const float* pby = pbx + NPIX;
  const float* pbd = pbx + 3*NPIX;
  const int*   ib  = inst + (size_t)b*NPIX;
  const int base = ch*2048 + g*128;        // group-private 128-px chunk
  float sloss = 0.f;
  #pragma unroll
  for (int it = 0; it < 2; ++it) {
    const int p = base + it*64 + l4*4;
    float4 px = *(const float4*)(pbx + p);
    float4 py = *(const float4*)(pby + p);
    int4   iv = *(const int4*)(ib + p);
    float4 dv = *(const float4*)(pbd + p);
    const float ym  = (float)(p >> 9) * inv;
    const float xm0 = (float)(p & (WW-1)) * inv;
    float pxa[4] = {px.x, px.y, px.z, px.w};
    float pya[4] = {py.x, py.y, py.z, py.w};
    int   ida[4] = {iv.x, iv.y, iv.z, iv.w};
    float sda[4] = {dv.x, dv.y, dv.z, dv.w};
    #pragma unroll
    for (int j = 0; j < 4; ++j) {
      float sex = fast_tanh(pxa[j]) + xm0 + (float)j*inv;
      float sey = fast_tanh(pya[j]) + ym;
      float s2 = fmaf(sex, sex, sey*sey);
      int id = ida[j];
      // branch-free: histogram ALL 16 k as background
      #pragma unroll
      for (int k = 0; k < KK; ++k) {
        float t2 = fmaf(seaL[k], s2, fmaf(AL[k], sex, fmaf(BL[k], sey, CL7[k])));
        float dN = __builtin_amdgcn_exp2f(t2);
        int bkt = (int)dN;
        bkt = bkt < (NB-1) ? bkt : (NB-1);
        atomicAdd(&lh[k][bkt], 1u);
      }
      if (id >= 1) {              // fg fixup: identical math via LDS co[]
        float c0 = co[id-1][0], c1 = co[id-1][1];
        float c2 = co[id-1][2], c3 = co[id-1][3];
        float t2o = fmaf(c0, s2, fmaf(c1, sex, fmaf(c2, sey, c3)));
        float dN  = __builtin_amdgcn_exp2f(t2o);
        int bktd = (int)dN;            bktd = bktd < (NB-1) ? bktd : (NB-1);
        int bktf = (int)(128.f - dN);  bktf = bktf < (NB-1) ? bktf : (NB-1);
        atomicAdd(&lh[id-1][bktd], 0xFFFFFFFFu);  // -1 from low field
        atomicAdd(&lh[id-1][bktf], 0x10001u);     // +1 to both fields
        float dwn = dN * 0.0078125f;              // d = dN/128
        float dsee = fast_sigmoid(sda[j]) - dwn;
        sloss = fmaf(dsee, dsee, sloss);
      }
    }
  }
  __syncthreads();
  // flush 16 hists -> disjoint global regions (plain coalesced stores)
  #pragma unroll
  for (int k = 0; k < KK; ++k) {
    unsigned int* gh = hist + ((size_t)(b*KK + k)*CHV + ch)*NB;
    if (tid < NB) gh[tid] = lh[k][tid];
  }
  #pragma unroll
  for (int off = 32; off; off >>= 1) sloss += __shfl_down(sloss, off);
  if ((tid & 63) == 0) lsl[tid >> 6] = sloss;
  __syncthreads();
  if (tid == 0) partial_v[bid] = lsl[0] + lsl[1] + lsl[2] + lsl[3];
}

// ---------------- kernel 3: lovasz (collapse + scan) + FUSED final --------
// grid 128. Computes its own cnt/var (spare lanes, overlapped with the
// collapse); publishes {cnt,var} to der2 before the done bump (release);
// the acquire fence orders them for the last block's combine.
// `done` never reset: (old & 127)==127 fires exactly once per call.
__global__ void __launch_bounds__(256) k_lovasz(
    const unsigned int* __restrict__ hist, const float* __restrict__ partial_s,
    const float* __restrict__ partial_v, const float* __restrict__ partial_b,
    float* __restrict__ instl, float* __restrict__ der2,
    unsigned int* __restrict__ done, float* __restrict__ out) {
  const int seg = blockIdx.x;
  const int b = seg >> 4, k = seg & 15;
  const int tid = threadIdx.x;
  __shared__ float nbL[NB], fbL[NB];
  __shared__ float s3[3];         // cnt, ss, sq
  __shared__ unsigned int sOld;
  const unsigned int* h = hist + (size_t)seg*CHV*NB;
  if (tid < NB) {
    unsigned int nlo = 0, nhi = 0;
    #pragma unroll 8
    for (int c = 0; c < CHV; ++c) {
      unsigned int v = h[(size_t)c*NB + tid];
      nlo += v & 0xffffu; nhi += v >> 16;
    }
    nbL[tid] = (float)nlo; fbL[tid] = (float)nhi;
  } else if (tid >= 128 && tid < 131) {  // fold cnt/ss/sq rows concurrently
    int comp = (tid == 128) ? 0 : (tid == 129) ? 3 : 4;
    const float* row = partial_s + ((size_t)b*80 + k*5 + comp)*CHS;
    float a = 0.f;
    #pragma unroll 8
    for (int c = 0; c < CHS; ++c) a += row[c];
    s3[tid - 128] = a;
  }
  __syncthreads();
  const float gts = s3[0];
  if (tid < 64) {
    const int lane = tid;
    float lsum = 0.f;
    if (gts > 0.f) {
      float carryN = 0.f, carryF = 0.f;
      #pragma unroll
      for (int it = 0; it < NB/64; ++it) {
        int bkt = NB - 1 - (it*64 + lane);
        float nb = nbL[bkt], fb = fbL[bkt];
        float sn = nb, sf = fb;
        #pragma unroll
        for (int off = 1; off < 64; off <<= 1) {
          float tn = __shfl_up(sn, off);
          float tf = __shfl_up(sf, off);
          if (lane >= off) { sn += tn; sf += tf; }
        }
        float Nb = carryN + sn - nb;
        float Fb = carryF + sf - fb;
        if (nb > 0.f) {
          float e  = ((float)bkt + 0.5f) * (2.0f/(float)NB);
          float j0 = 1.f - (gts - Fb) / (gts + Nb - Fb);
          float N1 = Nb + nb, F1 = Fb + fb;
          float j1 = 1.f - (gts - F1) / (gts + N1 - F1);
          lsum += e * (j1 - j0);
        }
        carryN += __shfl(sn, 63);
        carryF += __shfl(sf, 63);
      }
      #pragma unroll
      for (int off = 32; off; off >>= 1) lsum += __shfl_down(lsum, off);
    }
    if (lane == 0) {
      float cnt = gts;
      float sb = s3[1] * fast_rcp(fmaxf(cnt, 1.f));
      instl[seg] = lsum;
      der2[seg*2 + 0] = cnt;
      der2[seg*2 + 1] = s3[2] - cnt*sb*sb;   // Σ(σ−s̄)² over mask
      __threadfence();
      sOld = atomicAdd(done, 1u);
    }
  }
  __syncthreads();
  if ((sOld & 127u) != 127u) return;
  __threadfence();
  // ---- final combine (all 256 threads) ----
  __shared__ float vtmp[256], btmp[256];
  {
    const int b8 = tid >> 5, j = tid & 31;
    float a = 0.f, c = 0.f;
    #pragma unroll
    for (int i = 0; i < 4; ++i) {
      a += partial_v[(size_t)(j + 32*i)*8 + b8];
      c += partial_b[(size_t)(j + 32*i)*8 + b8];
    }
    vtmp[tid] = a; btmp[tid] = c;
  }
  __syncthreads();
  float myv = 0.f;
  if (tid < BB) {
    int bb = tid;
    float svl = 0.f, sbg = 0.f;
    #pragma unroll
    for (int j = 0; j < 32; ++j) { svl += vtmp[bb*32 + j]; sbg += btmp[bb*32 + j]; }
    float obj = 0.f, il = 0.f, vr = 0.f;
    for (int kk = 0; kk < KK; ++kk) {
      int s2 = bb*KK + kk;
      float cnt = der2[s2*2 + 0];
      if (cnt > 0.f) {
        obj += 1.f;
        il  += instl[s2];
        vr  += der2[s2*2 + 1] / cnt;     // var/(N_SIGMA*safe), safe==cnt
      }
    }
    float so = fmaxf(obj, 1.f);
    myv = il/so + 10.f*vr/so + (sbg + svl)/(float)NPIX;
  }
  #pragma unroll
  for (int off = 4; off; off >>= 1) myv += __shfl_down(myv, off);
  if (tid == 0) out[0] = myv * (1.f/(float)BB);
}

extern "C" void kernel_launch(void* const* d_in, const int* in_sizes, int n_in,
                              void* d_out, int out_size, void* d_ws, size_t ws_size,
                              hipStream_t stream) {
  const float* pred = (const float*)d_in[0];
  const int*   inst = (const int*)d_in[1];
  const int*   lab  = (const int*)d_in[2];
  float* out = (float*)d_out;

  // ws layout (~9.1 MB of 256 MiB); all consumed regions written every call.
  float* instl       = (float*)d_ws;                          // 128 f32
  float* der2        = (float*)((char*)d_ws + 1024);          // 256 f32
  unsigned int* done = (unsigned int*)((char*)d_ws + 2048);   // never reset
  float* partial_b   = (float*)((char*)d_ws + 8192);          // 1024 f32
  float* partial_v   = (float*)((char*)d_ws + 16384);         // 1024 f32
  float* partial_s   = (float*)((char*)d_ws + 24576);         // 8*80*128 f32
  unsigned int* hist = (unsigned int*)((char*)d_ws + 679936); // 128*128*128*4

  k_sums  <<<BB*CHS, 256, 0, stream>>>(pred, inst, lab, partial_s, partial_b);
  k_hist  <<<BB*CHV, 256, 0, stream>>>(pred, inst, partial_s, hist, partial_v);
  k_lovasz<<<BB*KK, 256, 0, stream>>>(hist, partial_s, partial_v, partial_b,
                                      instl, der2, done, out);
}